// Round 5
// baseline (457.898 us; speedup 1.0000x reference)
//
#include <hip/hip_runtime.h>
#include <hip/hip_bf16.h>

// ---- types ----
typedef __attribute__((ext_vector_type(8))) short v8s;   // 8 x bf16
typedef __attribute__((ext_vector_type(4))) short v4s;   // 4 x bf16
typedef __attribute__((ext_vector_type(4))) float v4f;
typedef __attribute__((ext_vector_type(16))) float v16f; // 32x32 MFMA C/D
typedef __attribute__((ext_vector_type(4))) unsigned v4u;

#define S_LEN 2048
#define NB 4
#define NH 16
#define LOG2E 1.4426950408889634f
// Mask constant: 1.3125 * 2^40 — EXACTLY representable in bf16 and fp32.
// Masked scores collapse to exactly -CMASK in fp32 (|s| << ulp/2 = 65536),
// so v_mask ties and causal ties stay bit-exact with each other.
#define CMASK 1443109011456.0f
#define DEFER_THR 11.55f                // ~8 * log2(e)  (T13)

__device__ __forceinline__ short f2bf(float f) {
    __hip_bfloat16 h = __float2bfloat16(f);
    union { __hip_bfloat16 h; short s; } u; u.h = h; return u.s;
}

__device__ __forceinline__ unsigned cvtpk(float lo, float hi) {
    unsigned r;
    asm("v_cvt_pk_bf16_f32 %0, %1, %2" : "=v"(r) : "v"(lo), "v"(hi));
    return r;
}

__device__ __forceinline__ void async16(void* lds, const void* g) {
    __builtin_amdgcn_global_load_lds(
        (const __attribute__((address_space(1))) unsigned int*)g,
        (__attribute__((address_space(3))) unsigned int*)lds, 16, 0, 0);
}

#define MFMA16(a, b, c) __builtin_amdgcn_mfma_f32_16x16x32_bf16((a), (b), (c), 0, 0, 0)
#define MFMA32(a, b, c) __builtin_amdgcn_mfma_f32_32x32x16_bf16((a), (b), (c), 0, 0, 0)

// ---------------- convert fp32 -> bf16 (vectorized, G13) ----------------
__global__ __launch_bounds__(256) void convert_f32_bf16(const float* __restrict__ in,
                                                        short* __restrict__ out) {
    size_t i = ((size_t)blockIdx.x * 256 + threadIdx.x) * 8;
    float4 a = *(const float4*)(in + i);
    float4 b = *(const float4*)(in + i + 4);
    v8s o;
    o[0] = f2bf(a.x); o[1] = f2bf(a.y); o[2] = f2bf(a.z); o[3] = f2bf(a.w);
    o[4] = f2bf(b.x); o[5] = f2bf(b.y); o[6] = f2bf(b.z); o[7] = f2bf(b.w);
    *(v8s*)(out + i) = o;
}

// ---------------- penalty column: pen[b][s] = vm ? 0 : -CMASK (bf16) -------
__global__ __launch_bounds__(256) void build_pen(const int* __restrict__ vm,
                                                 short* __restrict__ penC) {
    int i = blockIdx.x * 256 + threadIdx.x;   // 8192 total
    penC[i] = vm[i] ? (short)0 : f2bf(-CMASK);
}

// ---------------- W[K][N] fp32 -> WT[N][K] bf16 ----------------
__global__ __launch_bounds__(256) void transpose_w(const float* __restrict__ W,
                                                   short* __restrict__ WT) {
    __shared__ float tile[32][33];
    int k0 = blockIdx.x * 32, n0 = blockIdx.y * 32;
    int tx = threadIdx.x & 31, ty = threadIdx.x >> 5;  // ty 0..7
#pragma unroll
    for (int i = 0; i < 4; ++i)
        tile[ty + i * 8][tx] = W[(size_t)(k0 + ty + i * 8) * 1024 + n0 + tx];
    __syncthreads();
#pragma unroll
    for (int i = 0; i < 4; ++i)
        WT[(size_t)(n0 + ty + i * 8) * 1024 + k0 + tx] = f2bf(tile[tx][ty + i * 8]);
}

// ---------------- fused QKV projection GEMM (m97 structure) ----------------
__global__ __launch_bounds__(256)
void proj_gemm(const short* __restrict__ Xq, const short* __restrict__ Xk,
               const short* __restrict__ Xv,
               const short* __restrict__ WTq, const short* __restrict__ WTk,
               const short* __restrict__ WTv,
               const float* __restrict__ bq, const float* __restrict__ bk,
               const float* __restrict__ bv,
               short* __restrict__ QW, short* __restrict__ KW, short* __restrict__ VT) {
    __shared__ short As[128 * 64];
    __shared__ short Bs[128 * 64];
    const int tid = threadIdx.x;
    const int l = tid & 63, w = tid >> 6;
    const int g = l >> 4, ql = l & 15;
    const int m0 = blockIdx.x * 128, n0 = blockIdx.y * 128;
    const int z = blockIdx.z;
    const short* A  = (z == 0) ? Xq : (z == 1) ? Xk : Xv;
    const short* BT = (z == 0) ? WTq : (z == 1) ? WTk : WTv;
    const float* bias = (z == 0) ? bq : (z == 1) ? bk : bv;
    const int wr = w >> 1, wc = w & 1;

    v4f acc[4][4] = {};

    for (int kt = 0; kt < 16; ++kt) {
        const int kk = kt * 64;
        __syncthreads();
#pragma unroll
        for (int i = 0; i < 4; ++i) {
            int ci = i * 256 + tid;
            int row = ci >> 3, c = ci & 7;
            async16((char*)As + (size_t)(i * 256 + w * 64) * 16,
                    A + (size_t)(m0 + row) * 1024 + kk + c * 8);
            async16((char*)Bs + (size_t)(i * 256 + w * 64) * 16,
                    BT + (size_t)(n0 + row) * 1024 + kk + c * 8);
        }
        __syncthreads();
#pragma unroll
        for (int ks = 0; ks < 2; ++ks) {
            v8s af[4], bfr[4];
#pragma unroll
            for (int mt = 0; mt < 4; ++mt)
                af[mt] = *(const v8s*)(As + (wr * 64 + mt * 16 + ql) * 64 + ks * 32 + g * 8);
#pragma unroll
            for (int nt = 0; nt < 4; ++nt)
                bfr[nt] = *(const v8s*)(Bs + (wc * 64 + nt * 16 + ql) * 64 + ks * 32 + g * 8);
#pragma unroll
            for (int mt = 0; mt < 4; ++mt)
#pragma unroll
                for (int nt = 0; nt < 4; ++nt)
                    acc[mt][nt] = MFMA16(af[mt], bfr[nt], acc[mt][nt]);
        }
    }

#pragma unroll
    for (int nt = 0; nt < 4; ++nt) {
        int col = n0 + wc * 64 + nt * 16 + ql;
        float bval = bias[col];
        int hh = col >> 6, dd = col & 63;
#pragma unroll
        for (int mt = 0; mt < 4; ++mt) {
#pragma unroll
            for (int r = 0; r < 4; ++r) {
                int gm = m0 + wr * 64 + mt * 16 + g * 4 + r;
                int bb = gm >> 11, ss = gm & 2047;
                float vv = acc[mt][nt][r] + bval;
                if (z == 0) {
                    vv *= 0.125f * LOG2E;  // 1/sqrt(64) * log2e folded into Q
                    QW[((size_t)(bb * NH + hh) * S_LEN + ss) * 64 + dd] = f2bf(vv);
                } else if (z == 1) {
                    KW[((size_t)(bb * NH + hh) * S_LEN + ss) * 64 + dd] = f2bf(vv);
                } else {
                    VT[((size_t)(bb * NH + hh) * 64 + dd) * S_LEN + ss] = f2bf(vv);
                }
            }
        }
    }
}

// ---------------- flash attention: barrier-free, LDS-free ----------------
// K/V per head (512KB) is L2-resident -> read fragments DIRECTLY from global
// (lesson m169: don't LDS-stage what L2 fits). No __syncthreads anywhere.
// 4 waves x 32 q-rows; wave handles chunk pair {c, 15-c} (~34 tiles, balanced).
// v_mask folded into a 5th MFMA K-slice (virtual dim 64: K=-pen, Q=1) ->
// masked scores collapse to exactly -CMASK in fp32. In-reg P via
// cvt_pk+permlane32_swap; T13 defer-max; T14 in-register double-buffer.
__global__ __launch_bounds__(256, 2)
void attn_kernel(const short* __restrict__ QW, const short* __restrict__ KW,
                 const short* __restrict__ VT, const short* __restrict__ penC,
                 short* __restrict__ O) {
    const int tid = threadIdx.x;
    const int w = tid >> 6, l = tid & 63;
    const int lq = l & 31, hi = l >> 5;
    // XCD-local decode: 8 heads per XCD -> K/V working set ~ L2-sized.
    const int bid = blockIdx.x;
    const int xcd = bid & 7, sseq = bid >> 3;
    const int bh = xcd * 8 + (sseq >> 3);
    const int pr = sseq & 7;
    const int b = bh >> 4, hd = bh & 15;

    const short* Qp = QW + (size_t)bh * S_LEN * 64;
    const short* Kp = KW + (size_t)bh * S_LEN * 64;
    const short* Vp = VT + (size_t)bh * 64 * S_LEN;
    const short* pp = penC + b * S_LEN;

    for (int half = 0; half < 2; ++half) {
        const int chunk = half ? (15 - pr) : pr;
        const int q0 = chunk * 128 + w * 32;
        const int q_glob = q0 + lq;
        const int NT = (q0 >> 6) + 1;          // causal tile count

        // Q fragments (B-operand of swapped QK^T): B[k=ks*16+hi*8+j][q=lq]
        v8s qf[4];
#pragma unroll
        for (int ks = 0; ks < 4; ++ks)
            qf[ks] = *(const v8s*)(Qp + (size_t)q_glob * 64 + ks * 16 + hi * 8);
        v8s qf4 = {};
        qf4[0] = hi ? (short)0 : (short)0x3F80;   // bf16(1.0) at virtual dim 64

        v16f accO[2] = {};
        float m_run = -INFINITY, l_run = 0.f;

        // in-register double buffers (static names - rule #20)
        v8s kfA[8], vfA[8], kfB[8], vfB[8];
        short pA0 = 0, pA1 = 0, pB0 = 0, pB1 = 0;

#define FLOAD(kt, kf, vf, p0, p1)                                              \
        {                                                                      \
            const int k0_ = (kt) * 64;                                         \
            const short* kb_ = Kp + (size_t)(k0_ + lq) * 64 + hi * 8;          \
            const short* vb_ = Vp + (size_t)lq * S_LEN + k0_ + hi * 8;         \
            _Pragma("unroll")                                                  \
            for (int ks = 0; ks < 4; ++ks) {                                   \
                kf[ks]     = *(const v8s*)(kb_ + ks * 16);                     \
                kf[ks + 4] = *(const v8s*)(kb_ + 32 * 64 + ks * 16);           \
                vf[ks]     = *(const v8s*)(vb_ + ks * 16);                     \
                vf[ks + 4] = *(const v8s*)(vb_ + 32 * S_LEN + ks * 16);        \
            }                                                                  \
            p0 = pp[k0_ + lq];                                                 \
            p1 = pp[k0_ + lq + 32];                                            \
        }

        auto compute = [&](const v8s* kf, const v8s* vf, short p0, short p1,
                           int kt, bool causal) {
            // QK^T: acc[t] covers kp rows t*32 + (j&3)+8*(j>>2)+4*hi, col q=lq
            v16f acc[2] = {};
            __builtin_amdgcn_s_setprio(1);
#pragma unroll
            for (int ks = 0; ks < 4; ++ks) {
                acc[0] = MFMA32(kf[ks], qf[ks], acc[0]);
                acc[1] = MFMA32(kf[ks + 4], qf[ks], acc[1]);
            }
            // 5th slice: penalty column (hi=0 lanes carry pen at k=64)
            v8s k4a = {}, k4b = {};
            k4a[0] = hi ? (short)0 : p0;
            k4b[0] = hi ? (short)0 : p1;
            acc[0] = MFMA32(k4a, qf4, acc[0]);
            acc[1] = MFMA32(k4b, qf4, acc[1]);
            __builtin_amdgcn_s_setprio(0);

            float s[32];
            float tmax = -INFINITY;
#pragma unroll
            for (int t = 0; t < 2; ++t)
#pragma unroll
                for (int j = 0; j < 16; ++j)
                    s[t * 16 + j] = acc[t][j];
            if (causal) {
#pragma unroll
                for (int t = 0; t < 2; ++t)
#pragma unroll
                    for (int j = 0; j < 16; ++j) {
                        int kp = kt * 64 + t * 32 + (j & 3) + 8 * (j >> 2) + 4 * hi;
                        if (kp > q_glob) s[t * 16 + j] -= CMASK;
                    }
            }
#pragma unroll
            for (int i = 0; i < 32; ++i) tmax = fmaxf(tmax, s[i]);
            tmax = fmaxf(tmax, __shfl_xor(tmax, 32, 64));

            // T13 defer-max
            if (__any(tmax > m_run + DEFER_THR)) {
                float mnew = fmaxf(m_run, tmax);
                float scale = exp2f(m_run - mnew);
                m_run = mnew;
                l_run *= scale;
#pragma unroll
                for (int j = 0; j < 16; ++j) {
                    float sc = __shfl(scale, (j & 3) + 8 * (j >> 2) + 4 * hi, 64);
                    accO[0][j] *= sc;
                    accO[1][j] *= sc;
                }
            }
            float psum = 0.f;
#pragma unroll
            for (int i = 0; i < 32; ++i) {
                float p = exp2f(s[i] - m_run);
                s[i] = p;
                psum += p;
            }
            psum += __shfl_xor(psum, 32, 64);
            l_run += psum;

            // P -> PV A-operand in registers (cvt_pk + permlane32_swap)
            v8s PA[4];
#pragma unroll
            for (int t = 0; t < 2; ++t)
#pragma unroll
                for (int sf = 0; sf < 2; ++sf) {
                    int base = t * 16 + sf * 8;
                    unsigned x0 = cvtpk(s[base + 0], s[base + 1]);
                    unsigned x1 = cvtpk(s[base + 2], s[base + 3]);
                    unsigned y0 = cvtpk(s[base + 4], s[base + 5]);
                    unsigned y1 = cvtpk(s[base + 6], s[base + 7]);
                    asm volatile("v_permlane32_swap_b32 %0, %1" : "+v"(x0), "+v"(y0));
                    asm volatile("v_permlane32_swap_b32 %0, %1" : "+v"(x1), "+v"(y1));
                    v4u wv; wv[0] = x0; wv[1] = x1; wv[2] = y0; wv[3] = y1;
                    union { v4u u; v8s s8; } cvt; cvt.u = wv;
                    PA[t * 2 + sf] = cvt.s8;
                }

            // PV: accO[dt] += P * V[kp][dt*32+lq]
            __builtin_amdgcn_s_setprio(1);
#pragma unroll
            for (int ks = 0; ks < 4; ++ks) {
                accO[0] = MFMA32(PA[ks], vf[ks], accO[0]);
                accO[1] = MFMA32(PA[ks], vf[ks + 4], accO[1]);
            }
            __builtin_amdgcn_s_setprio(0);
        };

        // main loop: in-register double-buffered prefetch, no barriers
        FLOAD(0, kfA, vfA, pA0, pA1);
        int kt = 0;
        while (true) {
            if (kt + 1 < NT) FLOAD(kt + 1, kfB, vfB, pB0, pB1);
            compute(kfA, vfA, pA0, pA1, kt, kt == NT - 1);
            ++kt; if (kt >= NT) break;
            if (kt + 1 < NT) FLOAD(kt + 1, kfA, vfA, pA0, pA1);
            compute(kfB, vfB, pB0, pB1, kt, kt == NT - 1);
            ++kt; if (kt >= NT) break;
        }

        // Rescue (per-wave): rows with ALL causal-valid keys masked tie with
        // future keys at exactly -CMASK (reference fp32 semantics).
        while (kt < 32 && __any(m_run < -1e11f)) {
            FLOAD(kt, kfA, vfA, pA0, pA1);
            compute(kfA, vfA, pA0, pA1, kt, true);
            ++kt;
        }
#undef FLOAD

        // epilogue: rows q=(j&3)+8*(j>>2)+4*hi, cols d = dt*32+lq
        float inv = 1.0f / l_run;
#pragma unroll
        for (int j = 0; j < 16; ++j) {
            int rowq = (j & 3) + 8 * (j >> 2) + 4 * hi;
            float iv = __shfl(inv, rowq, 64);
            size_t base = (size_t)(b * S_LEN + q0 + rowq) * 1024 + hd * 64 + lq;
            O[base]      = f2bf(accO[0][j] * iv);
            O[base + 32] = f2bf(accO[1][j] * iv);
        }
    }
}

// ---------------- output projection + bias + q_mask ----------------
__global__ __launch_bounds__(256)
void out_gemm(const short* __restrict__ A, const short* __restrict__ BT,
              const float* __restrict__ bias, const int* __restrict__ qmask,
              float* __restrict__ out) {
    __shared__ short As[128 * 64];
    __shared__ short Bs[128 * 64];
    const int tid = threadIdx.x;
    const int l = tid & 63, w = tid >> 6;
    const int g = l >> 4, ql = l & 15;
    const int m0 = blockIdx.x * 128, n0 = blockIdx.y * 128;
    const int wr = w >> 1, wc = w & 1;

    v4f acc[4][4] = {};

    for (int kt = 0; kt < 16; ++kt) {
        const int kk = kt * 64;
        __syncthreads();
#pragma unroll
        for (int i = 0; i < 4; ++i) {
            int ci = i * 256 + tid;
            int row = ci >> 3, c = ci & 7;
            async16((char*)As + (size_t)(i * 256 + w * 64) * 16,
                    A + (size_t)(m0 + row) * 1024 + kk + c * 8);
            async16((char*)Bs + (size_t)(i * 256 + w * 64) * 16,
                    BT + (size_t)(n0 + row) * 1024 + kk + c * 8);
        }
        __syncthreads();
#pragma unroll
        for (int ks = 0; ks < 2; ++ks) {
            v8s af[4], bfr[4];
#pragma unroll
            for (int mt = 0; mt < 4; ++mt)
                af[mt] = *(const v8s*)(As + (wr * 64 + mt * 16 + ql) * 64 + ks * 32 + g * 8);
#pragma unroll
            for (int nt = 0; nt < 4; ++nt)
                bfr[nt] = *(const v8s*)(Bs + (wc * 64 + nt * 16 + ql) * 64 + ks * 32 + g * 8);
#pragma unroll
            for (int mt = 0; mt < 4; ++mt)
#pragma unroll
                for (int nt = 0; nt < 4; ++nt)
                    acc[mt][nt] = MFMA16(af[mt], bfr[nt], acc[mt][nt]);
        }
    }

#pragma unroll
    for (int nt = 0; nt < 4; ++nt) {
        int col = n0 + wc * 64 + nt * 16 + ql;
        float bval = bias[col];
#pragma unroll
        for (int mt = 0; mt < 4; ++mt) {
#pragma unroll
            for (int r = 0; r < 4; ++r) {
                int gm = m0 + wr * 64 + mt * 16 + g * 4 + r;
                float vv = acc[mt][nt][r] + bval;
                vv *= (float)qmask[gm];
                out[(size_t)gm * 1024 + col] = vv;
            }
        }
    }
}

extern "C" void kernel_launch(void* const* d_in, const int* in_sizes, int n_in,
                              void* d_out, int out_size, void* d_ws, size_t ws_size,
                              hipStream_t stream) {
    (void)in_sizes; (void)n_in; (void)out_size; (void)ws_size;
    const float* q  = (const float*)d_in[0];
    const float* k  = (const float*)d_in[1];
    const float* v  = (const float*)d_in[2];
    const int* qmask = (const int*)d_in[3];
    const int* vmask = (const int*)d_in[4];
    const float* Wq = (const float*)d_in[5];
    const float* bq = (const float*)d_in[6];
    const float* Wk = (const float*)d_in[7];
    const float* bk = (const float*)d_in[8];
    const float* Wv = (const float*)d_in[9];
    const float* bv = (const float*)d_in[10];
    const float* Wo = (const float*)d_in[11];
    const float* bo = (const float*)d_in[12];
    float* out = (float*)d_out;

    char* ws = (char*)d_ws;
    const size_t MB = 1024 * 1024;
    short* Xq  = (short*)(ws + 0 * MB);
    short* Xk  = (short*)(ws + 16 * MB);
    short* Xv  = (short*)(ws + 32 * MB);
    short* WTq = (short*)(ws + 48 * MB);
    short* WTk = (short*)(ws + 50 * MB);
    short* WTv = (short*)(ws + 52 * MB);
    short* WTo = (short*)(ws + 54 * MB);
    short* QW  = (short*)(ws + 56 * MB);
    short* KW  = (short*)(ws + 72 * MB);
    short* VTb = (short*)(ws + 88 * MB);
    short* Ob  = (short*)(ws + 104 * MB);
    short* penC = (short*)(ws + 120 * MB);

    convert_f32_bf16<<<4096, 256, 0, stream>>>(q, Xq);
    convert_f32_bf16<<<4096, 256, 0, stream>>>(k, Xk);
    convert_f32_bf16<<<4096, 256, 0, stream>>>(v, Xv);
    transpose_w<<<dim3(32, 32), 256, 0, stream>>>(Wq, WTq);
    transpose_w<<<dim3(32, 32), 256, 0, stream>>>(Wk, WTk);
    transpose_w<<<dim3(32, 32), 256, 0, stream>>>(Wv, WTv);
    transpose_w<<<dim3(32, 32), 256, 0, stream>>>(Wo, WTo);
    build_pen<<<32, 256, 0, stream>>>(vmask, penC);

    proj_gemm<<<dim3(64, 8, 3), 256, 0, stream>>>(Xq, Xk, Xv, WTq, WTk, WTv,
                                                  bq, bk, bv, QW, KW, VTb);
    attn_kernel<<<512, 256, 0, stream>>>(QW, KW, VTb, penC, Ob);
    out_gemm<<<dim3(64, 8), 256, 0, stream>>>(Ob, WTo, bo, qmask, out);
}

// Round 6
// 342.201 us; speedup vs baseline: 1.3381x; 1.3381x over previous
//
#include <hip/hip_runtime.h>
#include <hip/hip_bf16.h>

// ---- types ----
typedef __attribute__((ext_vector_type(8))) short v8s;   // 8 x bf16
typedef __attribute__((ext_vector_type(4))) short v4s;   // 4 x bf16
typedef __attribute__((ext_vector_type(4))) float v4f;
typedef __attribute__((ext_vector_type(16))) float v16f; // 32x32 MFMA C/D
typedef __attribute__((ext_vector_type(4))) unsigned v4u;

#define S_LEN 2048
#define NB 4
#define NH 16
#define LOG2E 1.4426950408889634f
#define C2MASK 1.4426950408889634e12f   // 1e12 * log2(e), fp32-collapses small addends
#define DEFER_THR 11.55f                // ~8 * log2(e)  (T13)

__device__ __forceinline__ short f2bf(float f) {
    __hip_bfloat16 h = __float2bfloat16(f);
    union { __hip_bfloat16 h; short s; } u; u.h = h; return u.s;
}

__device__ __forceinline__ unsigned cvtpk(float lo, float hi) {
    unsigned r;
    asm("v_cvt_pk_bf16_f32 %0, %1, %2" : "=v"(r) : "v"(lo), "v"(hi));
    return r;
}

// XOR swizzle for [R][128B] LDS tiles: per 16-lane quarter, 16 rows spread
// over 8 x 16B slots = 2-way = free (m136).
__device__ __forceinline__ int swz(int row, int col) {
    return (row * 128 + col) ^ ((row & 7) << 4);
}

__device__ __forceinline__ void async16(void* lds, const void* g) {
    __builtin_amdgcn_global_load_lds(
        (const __attribute__((address_space(1))) unsigned int*)g,
        (__attribute__((address_space(3))) unsigned int*)lds, 16, 0, 0);
}

#define MFMA16(a, b, c) __builtin_amdgcn_mfma_f32_16x16x32_bf16((a), (b), (c), 0, 0, 0)
#define MFMA32(a, b, c) __builtin_amdgcn_mfma_f32_32x32x16_bf16((a), (b), (c), 0, 0, 0)

// ---------------- convert fp32 -> bf16 (vectorized, G13) ----------------
__global__ __launch_bounds__(256) void convert_f32_bf16(const float* __restrict__ in,
                                                        short* __restrict__ out) {
    size_t i = ((size_t)blockIdx.x * 256 + threadIdx.x) * 8;
    float4 a = *(const float4*)(in + i);
    float4 b = *(const float4*)(in + i + 4);
    v8s o;
    o[0] = f2bf(a.x); o[1] = f2bf(a.y); o[2] = f2bf(a.z); o[3] = f2bf(a.w);
    o[4] = f2bf(b.x); o[5] = f2bf(b.y); o[6] = f2bf(b.z); o[7] = f2bf(b.w);
    *(v8s*)(out + i) = o;
}

// ---------------- W[K][N] fp32 -> WT[N][K] bf16 ----------------
__global__ __launch_bounds__(256) void transpose_w(const float* __restrict__ W,
                                                   short* __restrict__ WT) {
    __shared__ float tile[32][33];
    int k0 = blockIdx.x * 32, n0 = blockIdx.y * 32;
    int tx = threadIdx.x & 31, ty = threadIdx.x >> 5;  // ty 0..7
#pragma unroll
    for (int i = 0; i < 4; ++i)
        tile[ty + i * 8][tx] = W[(size_t)(k0 + ty + i * 8) * 1024 + n0 + tx];
    __syncthreads();
#pragma unroll
    for (int i = 0; i < 4; ++i)
        WT[(size_t)(n0 + ty + i * 8) * 1024 + k0 + tx] = f2bf(tile[tx][ty + i * 8]);
}

// ---------------- fused QKV projection GEMM (m97 structure) ----------------
__global__ __launch_bounds__(256)
void proj_gemm(const short* __restrict__ Xq, const short* __restrict__ Xk,
               const short* __restrict__ Xv,
               const short* __restrict__ WTq, const short* __restrict__ WTk,
               const short* __restrict__ WTv,
               const float* __restrict__ bq, const float* __restrict__ bk,
               const float* __restrict__ bv,
               short* __restrict__ QW, short* __restrict__ KW, short* __restrict__ VT) {
    __shared__ short As[128 * 64];
    __shared__ short Bs[128 * 64];
    const int tid = threadIdx.x;
    const int l = tid & 63, w = tid >> 6;
    const int g = l >> 4, ql = l & 15;
    const int m0 = blockIdx.x * 128, n0 = blockIdx.y * 128;
    const int z = blockIdx.z;
    const short* A  = (z == 0) ? Xq : (z == 1) ? Xk : Xv;
    const short* BT = (z == 0) ? WTq : (z == 1) ? WTk : WTv;
    const float* bias = (z == 0) ? bq : (z == 1) ? bk : bv;
    const int wr = w >> 1, wc = w & 1;

    v4f acc[4][4] = {};

    for (int kt = 0; kt < 16; ++kt) {
        const int kk = kt * 64;
        __syncthreads();
#pragma unroll
        for (int i = 0; i < 4; ++i) {
            int ci = i * 256 + tid;
            int row = ci >> 3, c = ci & 7;
            async16((char*)As + (size_t)(i * 256 + w * 64) * 16,
                    A + (size_t)(m0 + row) * 1024 + kk + c * 8);
            async16((char*)Bs + (size_t)(i * 256 + w * 64) * 16,
                    BT + (size_t)(n0 + row) * 1024 + kk + c * 8);
        }
        __syncthreads();
#pragma unroll
        for (int ks = 0; ks < 2; ++ks) {
            v8s af[4], bfr[4];
#pragma unroll
            for (int mt = 0; mt < 4; ++mt)
                af[mt] = *(const v8s*)(As + (wr * 64 + mt * 16 + ql) * 64 + ks * 32 + g * 8);
#pragma unroll
            for (int nt = 0; nt < 4; ++nt)
                bfr[nt] = *(const v8s*)(Bs + (wc * 64 + nt * 16 + ql) * 64 + ks * 32 + g * 8);
#pragma unroll
            for (int mt = 0; mt < 4; ++mt)
#pragma unroll
                for (int nt = 0; nt < 4; ++nt)
                    acc[mt][nt] = MFMA16(af[mt], bfr[nt], acc[mt][nt]);
        }
    }

#pragma unroll
    for (int nt = 0; nt < 4; ++nt) {
        int col = n0 + wc * 64 + nt * 16 + ql;
        float bval = bias[col];
        int hh = col >> 6, dd = col & 63;
#pragma unroll
        for (int mt = 0; mt < 4; ++mt) {
#pragma unroll
            for (int r = 0; r < 4; ++r) {
                int gm = m0 + wr * 64 + mt * 16 + g * 4 + r;
                int bb = gm >> 11, ss = gm & 2047;
                float vv = acc[mt][nt][r] + bval;
                if (z == 0) {
                    vv *= 0.125f * LOG2E;  // 1/sqrt(64) * log2e folded into Q
                    QW[((size_t)(bb * NH + hh) * S_LEN + ss) * 64 + dd] = f2bf(vv);
                } else if (z == 1) {
                    KW[((size_t)(bb * NH + hh) * S_LEN + ss) * 64 + dd] = f2bf(vv);
                } else {
                    VT[((size_t)(bb * NH + hh) * 64 + dd) * S_LEN + ss] = f2bf(vv);
                }
            }
        }
    }
}

// ---------------- flash attention (4-wave blocks, 2 blocks/CU) ----------------
// grid (64 bh, 8 pr); block handles 128-row chunks {pr, 15-pr} sequentially
// -> exactly 34 K-tiles per block (perfect balance). 4 waves x 32 q-rows.
// KVBLK=64. Swapped QK^T (32x32x16), in-reg P via cvt_pk+permlane32_swap,
// LDS K/V double-buffer (1 barrier/tile), T13 defer-max, T5 setprio.
// 2 blocks/CU resident -> independent barrier domains backfill each other
// (R4's single 512-thr block/CU had zero backfill; R5's reg-buffers spilled).
__global__ __launch_bounds__(256)
void attn_kernel(const short* __restrict__ QW, const short* __restrict__ KW,
                 const short* __restrict__ VT, const int* __restrict__ v_mask,
                 short* __restrict__ O) {
    __shared__ short Ks[2][64 * 64];  // [kp][d], row-XOR swizzled
    __shared__ short Vs[2][64 * 64];  // [d][kp], row-XOR swizzled
    __shared__ float pf[2][64];       // (1-vm)*C2MASK penalty per key
    __shared__ int rflag;

    const int tid = threadIdx.x;
    const int l = tid & 63, w = tid >> 6;     // w in 0..3
    const int lq = l & 31, hi = l >> 5;
    const int bh = blockIdx.x, pr = blockIdx.y;
    const int b = bh >> 4, hd = bh & 15;

    const short* Qp = QW + (size_t)bh * S_LEN * 64;
    const short* Kp = KW + (size_t)bh * S_LEN * 64;
    const short* Vp = VT + (size_t)bh * 64 * S_LEN;
    const int* vm = v_mask + b * S_LEN;

    for (int half = 0; half < 2; ++half) {
        const int qb = half ? (15 - pr) : pr;   // 128-row chunk index
        const int qw0 = qb * 128 + w * 32;      // this wave's first q-row
        const int q_glob = qw0 + lq;            // this lane's q-row

        // Q fragments (B-operand of swapped QK^T): B[k=ks*16+hi*8+j][q=lq]
        v8s qf[4];
#pragma unroll
        for (int ks = 0; ks < 4; ++ks)
            qf[ks] = *(const v8s*)(Qp + (size_t)q_glob * 64 + ks * 16 + hi * 8);

        v16f accO[2] = {};
        float m_run = -INFINITY, l_run = 0.f;

        // staging regs: 256 threads x 2 chunks of 16B per tensor (8KB tiles)
        v8s kA[2], vA[2]; int vmA = 0;

        auto gload = [&](int kt) {
            const int k0 = kt * 64;
#pragma unroll
            for (int i = 0; i < 2; ++i) {
                int slot = i * 256 + tid;
                int row = slot >> 3, c = slot & 7;
                kA[i] = *(const v8s*)(Kp + (size_t)(k0 + row) * 64 + c * 8);
                vA[i] = *(const v8s*)(Vp + (size_t)row * S_LEN + k0 + c * 8);
            }
            vmA = (tid < 64) ? vm[k0 + tid] : 0;
        };
        auto swrite = [&](int buf) {
#pragma unroll
            for (int i = 0; i < 2; ++i) {
                int slot = i * 256 + tid;
                int row = slot >> 3, c = slot & 7;
                *(v8s*)((char*)Ks[buf] + swz(row, c * 16)) = kA[i];
                *(v8s*)((char*)Vs[buf] + swz(row, c * 16)) = vA[i];
            }
            if (tid < 64) pf[buf][tid] = (1.0f - (float)vmA) * C2MASK;
        };

        auto chalf = [&](int kt, int buf, bool causal) {
            const int k0 = kt * 64;
            const short* Kb = Ks[buf];
            const short* Vb = Vs[buf];
            const float* pb = pf[buf];

            // QK^T: acc[t] covers kp rows t*32 + (j&3)+8*(j>>2)+4*hi, col q=lq
            v16f acc[2] = {};
            __builtin_amdgcn_s_setprio(1);
#pragma unroll
            for (int ks = 0; ks < 4; ++ks) {
                v8s k0f = *(const v8s*)((char*)Kb + swz(lq, ks * 32 + hi * 16));
                v8s k1f = *(const v8s*)((char*)Kb + swz(32 + lq, ks * 32 + hi * 16));
                acc[0] = MFMA32(k0f, qf[ks], acc[0]);
                acc[1] = MFMA32(k1f, qf[ks], acc[1]);
            }
            __builtin_amdgcn_s_setprio(0);

            // penalties (broadcast v4f reads) + optional causal, then row max
            float s[32];
            float tmax = -INFINITY;
#pragma unroll
            for (int t = 0; t < 2; ++t)
#pragma unroll
                for (int a = 0; a < 4; ++a) {
                    v4f pen = *(const v4f*)(pb + t * 32 + a * 8 + hi * 4);
#pragma unroll
                    for (int r = 0; r < 4; ++r)
                        s[t * 16 + a * 4 + r] = acc[t][a * 4 + r] - pen[r];
                }
            if (causal) {
#pragma unroll
                for (int t = 0; t < 2; ++t)
#pragma unroll
                    for (int j = 0; j < 16; ++j) {
                        int kp = k0 + t * 32 + (j & 3) + 8 * (j >> 2) + 4 * hi;
                        if (kp > q_glob) s[t * 16 + j] -= C2MASK;
                    }
            }
#pragma unroll
            for (int i = 0; i < 32; ++i) tmax = fmaxf(tmax, s[i]);
            tmax = fmaxf(tmax, __shfl_xor(tmax, 32, 64));

            // T13 defer-max: only rescale when max grew past threshold
            if (__any(tmax > m_run + DEFER_THR)) {
                float mnew = fmaxf(m_run, tmax);
                float scale = exp2f(m_run - mnew);
                m_run = mnew;
                l_run *= scale;
#pragma unroll
                for (int j = 0; j < 16; ++j) {
                    float sc = __shfl(scale, (j & 3) + 8 * (j >> 2) + 4 * hi, 64);
                    accO[0][j] *= sc;
                    accO[1][j] *= sc;
                }
            }
            float psum = 0.f;
#pragma unroll
            for (int i = 0; i < 32; ++i) {
                float p = exp2f(s[i] - m_run);
                s[i] = p;
                psum += p;
            }
            psum += __shfl_xor(psum, 32, 64);
            l_run += psum;

            // P -> PV A-operand in registers (cvt_pk + permlane32_swap)
            v8s PA[4];
#pragma unroll
            for (int t = 0; t < 2; ++t)
#pragma unroll
                for (int sf = 0; sf < 2; ++sf) {
                    int base = t * 16 + sf * 8;
                    unsigned x0 = cvtpk(s[base + 0], s[base + 1]);
                    unsigned x1 = cvtpk(s[base + 2], s[base + 3]);
                    unsigned y0 = cvtpk(s[base + 4], s[base + 5]);
                    unsigned y1 = cvtpk(s[base + 6], s[base + 7]);
                    asm volatile("v_permlane32_swap_b32 %0, %1" : "+v"(x0), "+v"(y0));
                    asm volatile("v_permlane32_swap_b32 %0, %1" : "+v"(x1), "+v"(y1));
                    v4u wv; wv[0] = x0; wv[1] = x1; wv[2] = y0; wv[3] = y1;
                    union { v4u u; v8s s8; } cvt; cvt.u = wv;
                    PA[t * 2 + sf] = cvt.s8;
                }

            // PV: A=P (in-reg), B=V[kp][d] via Vs=[d][kp]
            __builtin_amdgcn_s_setprio(1);
#pragma unroll
            for (int ks = 0; ks < 4; ++ks) {
                v8s v0f = *(const v8s*)((char*)Vb + swz(lq, ks * 32 + hi * 16));
                v8s v1f = *(const v8s*)((char*)Vb + swz(32 + lq, ks * 32 + hi * 16));
                accO[0] = MFMA32(PA[ks], v0f, accO[0]);
                accO[1] = MFMA32(PA[ks], v1f, accO[1]);
            }
            __builtin_amdgcn_s_setprio(0);
        };

        // main causal loop: LDS dbuf, ONE barrier per tile, T14 reg prefetch
        const int last = 2 * qb + 1;
        gload(0);
        __syncthreads();           // protect buffer reuse across halves
        swrite(0);
        gload(1);
        for (int kt = 0; kt <= last; ++kt) {
            __syncthreads();
            if (kt < last) {
                swrite((kt + 1) & 1);
                if (kt + 1 < last) gload(kt + 2);
            }
            chalf(kt, kt & 1, kt * 64 + 63 > qw0);
        }

        // Rescue pass: rows whose causal-valid keys are ALL masked must tie
        // with future keys at exactly -C2MASK (fp32 reference semantics).
        for (int kt = last + 1; kt < 32; ++kt) {
            if (tid == 0) rflag = 0;
            __syncthreads();
            if (__any(m_run < -1e11f) && l == 0) rflag = 1;
            __syncthreads();
            if (!rflag) break;
            gload(kt);
            swrite(0);
            __syncthreads();
            chalf(kt, 0, true);
        }

        // epilogue: rows q=(j&3)+8*(j>>2)+4*hi, cols d = dt*32+lq
        float inv = 1.0f / l_run;
#pragma unroll
        for (int j = 0; j < 16; ++j) {
            int rowq = (j & 3) + 8 * (j >> 2) + 4 * hi;
            float iv = __shfl(inv, rowq, 64);
            size_t base = (size_t)(b * S_LEN + qw0 + rowq) * 1024 + hd * 64 + lq;
            O[base]      = f2bf(accO[0][j] * iv);
            O[base + 32] = f2bf(accO[1][j] * iv);
        }
    }
}

// ---------------- output projection + bias + q_mask ----------------
__global__ __launch_bounds__(256)
void out_gemm(const short* __restrict__ A, const short* __restrict__ BT,
              const float* __restrict__ bias, const int* __restrict__ qmask,
              float* __restrict__ out) {
    __shared__ short As[128 * 64];
    __shared__ short Bs[128 * 64];
    const int tid = threadIdx.x;
    const int l = tid & 63, w = tid >> 6;
    const int g = l >> 4, ql = l & 15;
    const int m0 = blockIdx.x * 128, n0 = blockIdx.y * 128;
    const int wr = w >> 1, wc = w & 1;

    v4f acc[4][4] = {};

    for (int kt = 0; kt < 16; ++kt) {
        const int kk = kt * 64;
        __syncthreads();
#pragma unroll
        for (int i = 0; i < 4; ++i) {
            int ci = i * 256 + tid;
            int row = ci >> 3, c = ci & 7;
            async16((char*)As + (size_t)(i * 256 + w * 64) * 16,
                    A + (size_t)(m0 + row) * 1024 + kk + c * 8);
            async16((char*)Bs + (size_t)(i * 256 + w * 64) * 16,
                    BT + (size_t)(n0 + row) * 1024 + kk + c * 8);
        }
        __syncthreads();
#pragma unroll
        for (int ks = 0; ks < 2; ++ks) {
            v8s af[4], bfr[4];
#pragma unroll
            for (int mt = 0; mt < 4; ++mt)
                af[mt] = *(const v8s*)(As + (wr * 64 + mt * 16 + ql) * 64 + ks * 32 + g * 8);
#pragma unroll
            for (int nt = 0; nt < 4; ++nt)
                bfr[nt] = *(const v8s*)(Bs + (wc * 64 + nt * 16 + ql) * 64 + ks * 32 + g * 8);
#pragma unroll
            for (int mt = 0; mt < 4; ++mt)
#pragma unroll
                for (int nt = 0; nt < 4; ++nt)
                    acc[mt][nt] = MFMA16(af[mt], bfr[nt], acc[mt][nt]);
        }
    }

#pragma unroll
    for (int nt = 0; nt < 4; ++nt) {
        int col = n0 + wc * 64 + nt * 16 + ql;
        float bval = bias[col];
#pragma unroll
        for (int mt = 0; mt < 4; ++mt) {
#pragma unroll
            for (int r = 0; r < 4; ++r) {
                int gm = m0 + wr * 64 + mt * 16 + g * 4 + r;
                float vv = acc[mt][nt][r] + bval;
                vv *= (float)qmask[gm];
                out[(size_t)gm * 1024 + col] = vv;
            }
        }
    }
}

extern "C" void kernel_launch(void* const* d_in, const int* in_sizes, int n_in,
                              void* d_out, int out_size, void* d_ws, size_t ws_size,
                              hipStream_t stream) {
    (void)in_sizes; (void)n_in; (void)out_size; (void)ws_size;
    const float* q  = (const float*)d_in[0];
    const float* k  = (const float*)d_in[1];
    const float* v  = (const float*)d_in[2];
    const int* qmask = (const int*)d_in[3];
    const int* vmask = (const int*)d_in[4];
    const float* Wq = (const float*)d_in[5];
    const float* bq = (const float*)d_in[6];
    const float* Wk = (const float*)d_in[7];
    const float* bk = (const float*)d_in[8];
    const float* Wv = (const float*)d_in[9];
    const float* bv = (const float*)d_in[10];
    const float* Wo = (const float*)d_in[11];
    const float* bo = (const float*)d_in[12];
    float* out = (float*)d_out;

    char* ws = (char*)d_ws;
    const size_t MB = 1024 * 1024;
    short* Xq  = (short*)(ws + 0 * MB);
    short* Xk  = (short*)(ws + 16 * MB);
    short* Xv  = (short*)(ws + 32 * MB);
    short* WTq = (short*)(ws + 48 * MB);
    short* WTk = (short*)(ws + 50 * MB);
    short* WTv = (short*)(ws + 52 * MB);
    short* WTo = (short*)(ws + 54 * MB);
    short* QW  = (short*)(ws + 56 * MB);
    short* KW  = (short*)(ws + 72 * MB);
    short* VTb = (short*)(ws + 88 * MB);
    short* Ob  = (short*)(ws + 104 * MB);

    convert_f32_bf16<<<4096, 256, 0, stream>>>(q, Xq);
    convert_f32_bf16<<<4096, 256, 0, stream>>>(k, Xk);
    convert_f32_bf16<<<4096, 256, 0, stream>>>(v, Xv);
    transpose_w<<<dim3(32, 32), 256, 0, stream>>>(Wq, WTq);
    transpose_w<<<dim3(32, 32), 256, 0, stream>>>(Wk, WTk);
    transpose_w<<<dim3(32, 32), 256, 0, stream>>>(Wv, WTv);
    transpose_w<<<dim3(32, 32), 256, 0, stream>>>(Wo, WTo);

    proj_gemm<<<dim3(64, 8, 3), 256, 0, stream>>>(Xq, Xk, Xv, WTq, WTk, WTv,
                                                  bq, bk, bv, QW, KW, VTb);
    attn_kernel<<<dim3(64, 8), 256, 0, stream>>>(QW, KW, VTb, vmask, Ob);
    out_gemm<<<dim3(64, 8), 256, 0, stream>>>(Ob, WTo, bo, qmask, out);
}

// Round 8
// 291.657 us; speedup vs baseline: 1.5700x; 1.1733x over previous
//
#include <hip/hip_runtime.h>
#include <hip/hip_bf16.h>

// ---- types ----
typedef __attribute__((ext_vector_type(8))) short v8s;   // 8 x bf16
typedef __attribute__((ext_vector_type(4))) short v4s;   // 4 x bf16
typedef __attribute__((ext_vector_type(4))) float v4f;
typedef __attribute__((ext_vector_type(16))) float v16f; // 32x32 MFMA C/D
typedef __attribute__((ext_vector_type(4))) unsigned v4u;

#define S_LEN 2048
#define NB 4
#define NH 16
#define LOG2E 1.4426950408889634f
// Mask constant: 1.3125 * 2^40 — EXACTLY representable in bf16 AND fp32.
// Masked scores collapse to exactly -CMASK in fp32 (|s| << ulp/2 = 65536),
// so v_mask ties and causal ties stay bit-exact with each other.
#define CMASK 1443109011456.0f
#define DEFER_THR 11.55f                // ~8 * log2(e)  (T13)

__device__ __forceinline__ short f2bf(float f) {
    __hip_bfloat16 h = __float2bfloat16(f);
    union { __hip_bfloat16 h; short s; } u; u.h = h; return u.s;
}

__device__ __forceinline__ unsigned cvtpk(float lo, float hi) {
    unsigned r;
    asm("v_cvt_pk_bf16_f32 %0, %1, %2" : "=v"(r) : "v"(lo), "v"(hi));
    return r;
}

// XOR swizzle for [R][128B] LDS tiles (read side).
__device__ __forceinline__ int swz(int row, int col) {
    return (row * 128 + col) ^ ((row & 7) << 4);
}

__device__ __forceinline__ void async16(void* lds, const void* g) {
    __builtin_amdgcn_global_load_lds(
        (const __attribute__((address_space(1))) unsigned int*)g,
        (__attribute__((address_space(3))) unsigned int*)lds, 16, 0, 0);
}

#define MFMA16(a, b, c) __builtin_amdgcn_mfma_f32_16x16x32_bf16((a), (b), (c), 0, 0, 0)
#define MFMA32(a, b, c) __builtin_amdgcn_mfma_f32_32x32x16_bf16((a), (b), (c), 0, 0, 0)

// ---------------- convert fp32 -> bf16 (vectorized, G13) ----------------
__global__ __launch_bounds__(256) void convert_f32_bf16(const float* __restrict__ in,
                                                        short* __restrict__ out) {
    size_t i = ((size_t)blockIdx.x * 256 + threadIdx.x) * 8;
    float4 a = *(const float4*)(in + i);
    float4 b = *(const float4*)(in + i + 4);
    v8s o;
    o[0] = f2bf(a.x); o[1] = f2bf(a.y); o[2] = f2bf(a.z); o[3] = f2bf(a.w);
    o[4] = f2bf(b.x); o[5] = f2bf(b.y); o[6] = f2bf(b.z); o[7] = f2bf(b.w);
    *(v8s*)(out + i) = o;
}

// ---------------- penalty column: pen[b][s] = vm ? 0 : -CMASK (bf16) -------
__global__ __launch_bounds__(256) void build_pen(const int* __restrict__ vm,
                                                 short* __restrict__ penC) {
    int i = blockIdx.x * 256 + threadIdx.x;   // 8192 total
    penC[i] = vm[i] ? (short)0 : f2bf(-CMASK);
}

// ---------------- W[K][N] fp32 -> WT[N][K] bf16 ----------------
__global__ __launch_bounds__(256) void transpose_w(const float* __restrict__ W,
                                                   short* __restrict__ WT) {
    __shared__ float tile[32][33];
    int k0 = blockIdx.x * 32, n0 = blockIdx.y * 32;
    int tx = threadIdx.x & 31, ty = threadIdx.x >> 5;  // ty 0..7
#pragma unroll
    for (int i = 0; i < 4; ++i)
        tile[ty + i * 8][tx] = W[(size_t)(k0 + ty + i * 8) * 1024 + n0 + tx];
    __syncthreads();
#pragma unroll
    for (int i = 0; i < 4; ++i)
        WT[(size_t)(n0 + ty + i * 8) * 1024 + k0 + tx] = f2bf(tile[tx][ty + i * 8]);
}

// ---------------- fused QKV projection GEMM (m97 structure) ----------------
__global__ __launch_bounds__(256)
void proj_gemm(const short* __restrict__ Xq, const short* __restrict__ Xk,
               const short* __restrict__ Xv,
               const short* __restrict__ WTq, const short* __restrict__ WTk,
               const short* __restrict__ WTv,
               const float* __restrict__ bq, const float* __restrict__ bk,
               const float* __restrict__ bv,
               short* __restrict__ QW, short* __restrict__ KW, short* __restrict__ VT) {
    __shared__ short As[128 * 64];
    __shared__ short Bs[128 * 64];
    const int tid = threadIdx.x;
    const int l = tid & 63, w = tid >> 6;
    const int g = l >> 4, ql = l & 15;
    const int m0 = blockIdx.x * 128, n0 = blockIdx.y * 128;
    const int z = blockIdx.z;
    const short* A  = (z == 0) ? Xq : (z == 1) ? Xk : Xv;
    const short* BT = (z == 0) ? WTq : (z == 1) ? WTk : WTv;
    const float* bias = (z == 0) ? bq : (z == 1) ? bk : bv;
    const int wr = w >> 1, wc = w & 1;

    v4f acc[4][4] = {};

    for (int kt = 0; kt < 16; ++kt) {
        const int kk = kt * 64;
        __syncthreads();
#pragma unroll
        for (int i = 0; i < 4; ++i) {
            int ci = i * 256 + tid;
            int row = ci >> 3, c = ci & 7;
            async16((char*)As + (size_t)(i * 256 + w * 64) * 16,
                    A + (size_t)(m0 + row) * 1024 + kk + c * 8);
            async16((char*)Bs + (size_t)(i * 256 + w * 64) * 16,
                    BT + (size_t)(n0 + row) * 1024 + kk + c * 8);
        }
        __syncthreads();
#pragma unroll
        for (int ks = 0; ks < 2; ++ks) {
            v8s af[4], bfr[4];
#pragma unroll
            for (int mt = 0; mt < 4; ++mt)
                af[mt] = *(const v8s*)(As + (wr * 64 + mt * 16 + ql) * 64 + ks * 32 + g * 8);
#pragma unroll
            for (int nt = 0; nt < 4; ++nt)
                bfr[nt] = *(const v8s*)(Bs + (wc * 64 + nt * 16 + ql) * 64 + ks * 32 + g * 8);
#pragma unroll
            for (int mt = 0; mt < 4; ++mt)
#pragma unroll
                for (int nt = 0; nt < 4; ++nt)
                    acc[mt][nt] = MFMA16(af[mt], bfr[nt], acc[mt][nt]);
        }
    }

#pragma unroll
    for (int nt = 0; nt < 4; ++nt) {
        int col = n0 + wc * 64 + nt * 16 + ql;
        float bval = bias[col];
        int hh = col >> 6, dd = col & 63;
#pragma unroll
        for (int mt = 0; mt < 4; ++mt) {
#pragma unroll
            for (int r = 0; r < 4; ++r) {
                int gm = m0 + wr * 64 + mt * 16 + g * 4 + r;
                int bb = gm >> 11, ss = gm & 2047;
                float vv = acc[mt][nt][r] + bval;
                if (z == 0) {
                    vv *= 0.125f * LOG2E;  // 1/sqrt(64) * log2e folded into Q
                    QW[((size_t)(bb * NH + hh) * S_LEN + ss) * 64 + dd] = f2bf(vv);
                } else if (z == 1) {
                    KW[((size_t)(bb * NH + hh) * S_LEN + ss) * 64 + dd] = f2bf(vv);
                } else {
                    VT[((size_t)(bb * NH + hh) * 64 + dd) * S_LEN + ss] = f2bf(vv);
                }
            }
        }
    }
}

// ---------------- flash attention (high-TLP, gload_lds staging) ----------------
// grid (64 bh, 16 y->qb coset map) = 1024 blocks, ALL co-resident at 4/CU.
// Dispatch puts blocks {y, y+4, y+8, y+12} on one CU; the coset qb map makes
// each such set sum to exactly 68 K-tiles (balanced). Staging = global_load_lds
// with PRE-SWIZZLED source (rule #21): linear LDS dest, source chunk
// c^=(row&7) == read-side swz(). Penalty via 5th MFMA K-slice (R5-proven).
// Cross-half reductions via __shfl_xor — NOT permlane32_swap on same-SSA
// inputs (R7 bug: RA coalesces a==c into one VGPR -> in-place swap drops
// this half's contribution). permlane only where SSA-distinct (PA build).
__global__ __launch_bounds__(256, 4)
void attn_kernel(const short* __restrict__ QW, const short* __restrict__ KW,
                 const short* __restrict__ VT, const short* __restrict__ penC,
                 short* __restrict__ O) {
    __shared__ short Ks[2][64 * 64];  // [kp][d], swizzled via source perm
    __shared__ short Vs[2][64 * 64];  // [d][kp], swizzled via source perm
    __shared__ int rflag;

    const int tid = threadIdx.x;
    const int l = tid & 63, w = tid >> 6;     // w in 0..3
    const int lq = l & 31, hi = l >> 5;
    const int bh = blockIdx.x, y = blockIdx.y;
    const int t4 = y >> 2;
    const int qb = (t4 & 1) ? ((t4 == 1) ? y + 4 : y - 12) : (15 - y);
    const int b = bh >> 4, hd = bh & 15;

    const short* Qp = QW + (size_t)bh * S_LEN * 64;
    const short* Kp = KW + (size_t)bh * S_LEN * 64;
    const short* Vp = VT + (size_t)bh * 64 * S_LEN;
    const short* pp = penC + b * S_LEN;

    const int qw0 = qb * 128 + w * 32;      // this wave's first q-row
    const int q_glob = qw0 + lq;            // this lane's q-row
    const int NT = 2 * qb + 2;              // causal tile count

    // pre-swizzled gload_lds source coords (per-lane constants)
    const int srow = l >> 3;                // row within 8-row segment
    const int scol = (l & 7) ^ srow;        // XOR involution == read swz

    // Q fragments (B-operand of swapped QK^T): B[k=ks*16+hi*8+j][q=lq]
    v8s qf[4];
#pragma unroll
    for (int ks = 0; ks < 4; ++ks)
        qf[ks] = *(const v8s*)(Qp + (size_t)q_glob * 64 + ks * 16 + hi * 8);
    v8s qf4 = {};
    qf4[0] = hi ? (short)0 : (short)0x3F80;   // bf16(1.0) at virtual k=64

    v16f accO[2] = {};
    float m_run = -INFINITY, l_run = 0.f;

    auto stage = [&](int kt, int buf) {
        const int k0 = kt * 64;
#pragma unroll
        for (int i = 0; i < 2; ++i) {
            const int s = w * 2 + i;            // wave-uniform segment id
            const int row = s * 8 + srow;
            async16((char*)Ks[buf] + s * 1024,
                    Kp + (size_t)(k0 + row) * 64 + scol * 8);
            async16((char*)Vs[buf] + s * 1024,
                    Vp + (size_t)row * S_LEN + k0 + scol * 8);
        }
    };

    auto chalf = [&](int kt, int buf, bool causal, short p0, short p1) {
        const short* Kb = Ks[buf];
        const short* Vb = Vs[buf];

        // QK^T: acc[t] rows kp = t*32+(j&3)+8*(j>>2)+4*hi, col q = lq
        v16f acc0 = {}, acc1 = {};
        __builtin_amdgcn_s_setprio(1);
#pragma unroll
        for (int ks = 0; ks < 4; ++ks) {
            v8s k0f = *(const v8s*)((char*)Kb + swz(lq, ks * 32 + hi * 16));
            v8s k1f = *(const v8s*)((char*)Kb + swz(32 + lq, ks * 32 + hi * 16));
            acc0 = MFMA32(k0f, qf[ks], acc0);
            acc1 = MFMA32(k1f, qf[ks], acc1);
        }
        // 5th slice: v_mask penalty column (hi=0 lanes carry pen at k=64)
        v8s k4a = {}, k4b = {};
        k4a[0] = hi ? (short)0 : p0;
        k4b[0] = hi ? (short)0 : p1;
        acc0 = MFMA32(k4a, qf4, acc0);
        acc1 = MFMA32(k4b, qf4, acc1);
        __builtin_amdgcn_s_setprio(0);

        float s[32];
#pragma unroll
        for (int j = 0; j < 16; ++j) { s[j] = acc0[j]; s[16 + j] = acc1[j]; }
        if (causal) {
#pragma unroll
            for (int t = 0; t < 2; ++t)
#pragma unroll
                for (int j = 0; j < 16; ++j) {
                    int kp = kt * 64 + t * 32 + (j & 3) + 8 * (j >> 2) + 4 * hi;
                    if (kp > q_glob) s[t * 16 + j] -= CMASK;
                }
        }
        // tree max (depth 5)
        float t8[8];
#pragma unroll
        for (int i = 0; i < 8; ++i)
            t8[i] = fmaxf(fmaxf(s[i], s[i + 8]), fmaxf(s[i + 16], s[i + 24]));
#pragma unroll
        for (int i = 0; i < 4; ++i) t8[i] = fmaxf(t8[i], t8[i + 4]);
        float tmax = fmaxf(fmaxf(t8[0], t8[1]), fmaxf(t8[2], t8[3]));
        tmax = fmaxf(tmax, __shfl_xor(tmax, 32, 64));   // cross-half (proven path)

        // T13 defer-max: only rescale when max grew past threshold
        if (__any(tmax > m_run + DEFER_THR)) {
            float mnew = fmaxf(m_run, tmax);
            float scale = exp2f(m_run - mnew);
            m_run = mnew;
            l_run *= scale;
#pragma unroll
            for (int j = 0; j < 16; ++j) {
                float sc = __shfl(scale, (j & 3) + 8 * (j >> 2) + 4 * hi, 64);
                accO[0][j] *= sc;
                accO[1][j] *= sc;
            }
        }
#pragma unroll
        for (int i = 0; i < 32; ++i) s[i] = exp2f(s[i] - m_run);
        // tree sum
        float u8[8];
#pragma unroll
        for (int i = 0; i < 8; ++i)
            u8[i] = (s[i] + s[i + 8]) + (s[i + 16] + s[i + 24]);
#pragma unroll
        for (int i = 0; i < 4; ++i) u8[i] += u8[i + 4];
        float psum = (u8[0] + u8[1]) + (u8[2] + u8[3]);
        psum += __shfl_xor(psum, 32, 64);               // cross-half (proven path)
        l_run += psum;

        // P -> PV A-operand in registers (cvt_pk + permlane32_swap;
        // operands here are SSA-distinct -> no coalescing hazard)
        v8s PA[4];
#pragma unroll
        for (int t = 0; t < 2; ++t)
#pragma unroll
            for (int sf = 0; sf < 2; ++sf) {
                int base = t * 16 + sf * 8;
                unsigned x0 = cvtpk(s[base + 0], s[base + 1]);
                unsigned x1 = cvtpk(s[base + 2], s[base + 3]);
                unsigned y0 = cvtpk(s[base + 4], s[base + 5]);
                unsigned y1 = cvtpk(s[base + 6], s[base + 7]);
                asm volatile("v_permlane32_swap_b32 %0, %1" : "+v"(x0), "+v"(y0));
                asm volatile("v_permlane32_swap_b32 %0, %1" : "+v"(x1), "+v"(y1));
                v4u wv; wv[0] = x0; wv[1] = x1; wv[2] = y0; wv[3] = y1;
                union { v4u u; v8s s8; } cvt; cvt.u = wv;
                PA[t * 2 + sf] = cvt.s8;
            }

        // PV: A=P (in-reg), B=V[kp][d] via Vs=[d][kp]
        __builtin_amdgcn_s_setprio(1);
#pragma unroll
        for (int ks = 0; ks < 4; ++ks) {
            v8s v0f = *(const v8s*)((char*)Vb + swz(lq, ks * 32 + hi * 16));
            v8s v1f = *(const v8s*)((char*)Vb + swz(32 + lq, ks * 32 + hi * 16));
            accO[0] = MFMA32(PA[ks], v0f, accO[0]);
            accO[1] = MFMA32(PA[ks], v1f, accO[1]);
        }
        __builtin_amdgcn_s_setprio(0);
    };

    // main causal loop: gload_lds dbuf, ONE barrier per tile
    stage(0, 0);
    __syncthreads();                         // drains vmcnt -> tile0 ready
    for (int kt = 0; kt < NT; ++kt) {
        const int k0 = kt * 64;
        // pen loads FIRST (oldest in vmcnt) so their wait leaves prefetch in flight
        short p0 = pp[k0 + lq], p1 = pp[k0 + lq + 32];
        __builtin_amdgcn_sched_barrier(0);   // pin: pen loads before prefetch
        if (kt + 1 < NT) stage(kt + 1, (kt + 1) & 1);
        chalf(kt, kt & 1, k0 + 63 > qw0, p0, p1);
        __syncthreads();                     // drain prefetch + buffer reuse sync
    }

    // Rescue pass: rows whose causal-valid keys are ALL masked must tie with
    // future keys at exactly -CMASK (fp32 reference semantics).
    int kt = NT;
    while (kt < 32) {
        if (tid == 0) rflag = 0;
        __syncthreads();
        if (__any(m_run < -1e11f) && l == 0) rflag = 1;
        __syncthreads();
        if (!rflag) break;
        short p0 = pp[kt * 64 + lq], p1 = pp[kt * 64 + lq + 32];
        stage(kt, 0);
        __syncthreads();
        chalf(kt, 0, true, p0, p1);
        __syncthreads();
        ++kt;
    }

    // epilogue: rows q=(j&3)+8*(j>>2)+4*hi, cols d = dt*32+lq
    float inv = 1.0f / l_run;
#pragma unroll
    for (int j = 0; j < 16; ++j) {
        int rowq = (j & 3) + 8 * (j >> 2) + 4 * hi;
        float iv = __shfl(inv, rowq, 64);
        size_t base = (size_t)(b * S_LEN + qw0 + rowq) * 1024 + hd * 64 + lq;
        O[base]      = f2bf(accO[0][j] * iv);
        O[base + 32] = f2bf(accO[1][j] * iv);
    }
}

// ---------------- output projection + bias + q_mask ----------------
__global__ __launch_bounds__(256)
void out_gemm(const short* __restrict__ A, const short* __restrict__ BT,
              const float* __restrict__ bias, const int* __restrict__ qmask,
              float* __restrict__ out) {
    __shared__ short As[128 * 64];
    __shared__ short Bs[128 * 64];
    const int tid = threadIdx.x;
    const int l = tid & 63, w = tid >> 6;
    const int g = l >> 4, ql = l & 15;
    const int m0 = blockIdx.x * 128, n0 = blockIdx.y * 128;
    const int wr = w >> 1, wc = w & 1;

    v4f acc[4][4] = {};

    for (int kt = 0; kt < 16; ++kt) {
        const int kk = kt * 64;
        __syncthreads();
#pragma unroll
        for (int i = 0; i < 4; ++i) {
            int ci = i * 256 + tid;
            int row = ci >> 3, c = ci & 7;
            async16((char*)As + (size_t)(i * 256 + w * 64) * 16,
                    A + (size_t)(m0 + row) * 1024 + kk + c * 8);
            async16((char*)Bs + (size_t)(i * 256 + w * 64) * 16,
                    BT + (size_t)(n0 + row) * 1024 + kk + c * 8);
        }
        __syncthreads();
#pragma unroll
        for (int ks = 0; ks < 2; ++ks) {
            v8s af[4], bfr[4];
#pragma unroll
            for (int mt = 0; mt < 4; ++mt)
                af[mt] = *(const v8s*)(As + (wr * 64 + mt * 16 + ql) * 64 + ks * 32 + g * 8);
#pragma unroll
            for (int nt = 0; nt < 4; ++nt)
                bfr[nt] = *(const v8s*)(Bs + (wc * 64 + nt * 16 + ql) * 64 + ks * 32 + g * 8);
#pragma unroll
            for (int mt = 0; mt < 4; ++mt)
#pragma unroll
                for (int nt = 0; nt < 4; ++nt)
                    acc[mt][nt] = MFMA16(af[mt], bfr[nt], acc[mt][nt]);
        }
    }

#pragma unroll
    for (int nt = 0; nt < 4; ++nt) {
        int col = n0 + wc * 64 + nt * 16 + ql;
        float bval = bias[col];
#pragma unroll
        for (int mt = 0; mt < 4; ++mt) {
#pragma unroll
            for (int r = 0; r < 4; ++r) {
                int gm = m0 + wr * 64 + mt * 16 + g * 4 + r;
                float vv = acc[mt][nt][r] + bval;
                vv *= (float)qmask[gm];
                out[(size_t)gm * 1024 + col] = vv;
            }
        }
    }
}

extern "C" void kernel_launch(void* const* d_in, const int* in_sizes, int n_in,
                              void* d_out, int out_size, void* d_ws, size_t ws_size,
                              hipStream_t stream) {
    (void)in_sizes; (void)n_in; (void)out_size; (void)ws_size;
    const float* q  = (const float*)d_in[0];
    const float* k  = (const float*)d_in[1];
    const float* v  = (const float*)d_in[2];
    const int* qmask = (const int*)d_in[3];
    const int* vmask = (const int*)d_in[4];
    const float* Wq = (const float*)d_in[5];
    const float* bq = (const float*)d_in[6];
    const float* Wk = (const float*)d_in[7];
    const float* bk = (const float*)d_in[8];
    const float* Wv = (const float*)d_in[9];
    const float* bv = (const float*)d_in[10];
    const float* Wo = (const float*)d_in[11];
    const float* bo = (const float*)d_in[12];
    float* out = (float*)d_out;

    char* ws = (char*)d_ws;
    const size_t MB = 1024 * 1024;
    short* Xq  = (short*)(ws + 0 * MB);
    short* Xk  = (short*)(ws + 16 * MB);
    short* Xv  = (short*)(ws + 32 * MB);
    short* WTq = (short*)(ws + 48 * MB);
    short* WTk = (short*)(ws + 50 * MB);
    short* WTv = (short*)(ws + 52 * MB);
    short* WTo = (short*)(ws + 54 * MB);
    short* QW  = (short*)(ws + 56 * MB);
    short* KW  = (short*)(ws + 72 * MB);
    short* VTb = (short*)(ws + 88 * MB);
    short* Ob  = (short*)(ws + 104 * MB);
    short* penC = (short*)(ws + 120 * MB);

    convert_f32_bf16<<<4096, 256, 0, stream>>>(q, Xq);
    convert_f32_bf16<<<4096, 256, 0, stream>>>(k, Xk);
    convert_f32_bf16<<<4096, 256, 0, stream>>>(v, Xv);
    transpose_w<<<dim3(32, 32), 256, 0, stream>>>(Wq, WTq);
    transpose_w<<<dim3(32, 32), 256, 0, stream>>>(Wk, WTk);
    transpose_w<<<dim3(32, 32), 256, 0, stream>>>(Wv, WTv);
    transpose_w<<<dim3(32, 32), 256, 0, stream>>>(Wo, WTo);
    build_pen<<<32, 256, 0, stream>>>(vmask, penC);

    proj_gemm<<<dim3(64, 8, 3), 256, 0, stream>>>(Xq, Xk, Xv, WTq, WTk, WTv,
                                                  bq, bk, bv, QW, KW, VTb);
    attn_kernel<<<dim3(64, 16), 256, 0, stream>>>(QW, KW, VTb, penC, Ob);
    out_gemm<<<dim3(64, 8), 256, 0, stream>>>(Ob, WTo, bo, qmask, out);
}

// Round 9
// 278.349 us; speedup vs baseline: 1.6450x; 1.0478x over previous
//
#include <hip/hip_runtime.h>
#include <hip/hip_bf16.h>

// ---- types ----
typedef __attribute__((ext_vector_type(8))) short v8s;   // 8 x bf16
typedef __attribute__((ext_vector_type(4))) short v4s;   // 4 x bf16
typedef __attribute__((ext_vector_type(4))) float v4f;
typedef __attribute__((ext_vector_type(16))) float v16f; // 32x32 MFMA C/D
typedef __attribute__((ext_vector_type(4))) unsigned v4u;

#define S_LEN 2048
#define NB 4
#define NH 16
#define LOG2E 1.4426950408889634f
// Mask constant: 1.3125 * 2^40 — EXACTLY representable in bf16 AND fp32.
// Masked scores collapse to exactly -CMASK in fp32 (|s| << ulp/2 = 32768),
// so v_mask ties and causal ties stay bit-exact with each other.
#define CMASK 1443109011456.0f
#define DEFER_THR 11.55f                // ~8 * log2(e)  (T13)

__device__ __forceinline__ short f2bf(float f) {
    __hip_bfloat16 h = __float2bfloat16(f);
    union { __hip_bfloat16 h; short s; } u; u.h = h; return u.s;
}

__device__ __forceinline__ unsigned cvtpk(float lo, float hi) {
    unsigned r;
    asm("v_cvt_pk_bf16_f32 %0, %1, %2" : "=v"(r) : "v"(lo), "v"(hi));
    return r;
}

// XOR swizzle for [R][128B] LDS tiles (read side).
__device__ __forceinline__ int swz(int row, int col) {
    return (row * 128 + col) ^ ((row & 7) << 4);
}

__device__ __forceinline__ void async16(void* lds, const void* g) {
    __builtin_amdgcn_global_load_lds(
        (const __attribute__((address_space(1))) unsigned int*)g,
        (__attribute__((address_space(3))) unsigned int*)lds, 16, 0, 0);
}

#define MFMA16(a, b, c) __builtin_amdgcn_mfma_f32_16x16x32_bf16((a), (b), (c), 0, 0, 0)
#define MFMA32(a, b, c) __builtin_amdgcn_mfma_f32_32x32x16_bf16((a), (b), (c), 0, 0, 0)

// ---------------- convert fp32 -> bf16 (vectorized, G13) ----------------
__global__ __launch_bounds__(256) void convert_f32_bf16(const float* __restrict__ in,
                                                        short* __restrict__ out) {
    size_t i = ((size_t)blockIdx.x * 256 + threadIdx.x) * 8;
    float4 a = *(const float4*)(in + i);
    float4 b = *(const float4*)(in + i + 4);
    v8s o;
    o[0] = f2bf(a.x); o[1] = f2bf(a.y); o[2] = f2bf(a.z); o[3] = f2bf(a.w);
    o[4] = f2bf(b.x); o[5] = f2bf(b.y); o[6] = f2bf(b.z); o[7] = f2bf(b.w);
    *(v8s*)(out + i) = o;
}

// ---------------- penalty column: pen[b][s] = vm ? 0 : -CMASK (bf16) -------
__global__ __launch_bounds__(256) void build_pen(const int* __restrict__ vm,
                                                 short* __restrict__ penC) {
    int i = blockIdx.x * 256 + threadIdx.x;   // 8192 total
    penC[i] = vm[i] ? (short)0 : f2bf(-CMASK);
}

// ------------- q_mask compaction: idx[b][j] = j-th live row, nq[b] ---------
// out = (o@Wo+bo)*q_mask -> q_mask=0 rows are dead work in attention.
__global__ __launch_bounds__(256) void compact_qmask(const int* __restrict__ qm,
                                                     int* __restrict__ idx,
                                                     int* __restrict__ nq) {
    const int b = blockIdx.x;
    const int* m = qm + b * S_LEN;
    int* ib = idx + b * S_LEN;
    __shared__ int cnt[256];
    const int t = threadIdx.x;
    int loc[8], c = 0;
#pragma unroll
    for (int i = 0; i < 8; ++i) { int s = t * 8 + i; if (m[s]) loc[c++] = s; }
    cnt[t] = c;
    __syncthreads();
    for (int d = 1; d < 256; d <<= 1) {       // Hillis-Steele inclusive scan
        int v = (t >= d) ? cnt[t - d] : 0;
        __syncthreads();
        cnt[t] += v;
        __syncthreads();
    }
    int off = cnt[t] - c;                     // exclusive prefix
    for (int i = 0; i < c; ++i) ib[off + i] = loc[i];
    if (t == 255) nq[b] = cnt[255];
}

// ---------------- W[K][N] fp32 -> WT[N][K] bf16 ----------------
__global__ __launch_bounds__(256) void transpose_w(const float* __restrict__ W,
                                                   short* __restrict__ WT) {
    __shared__ float tile[32][33];
    int k0 = blockIdx.x * 32, n0 = blockIdx.y * 32;
    int tx = threadIdx.x & 31, ty = threadIdx.x >> 5;  // ty 0..7
#pragma unroll
    for (int i = 0; i < 4; ++i)
        tile[ty + i * 8][tx] = W[(size_t)(k0 + ty + i * 8) * 1024 + n0 + tx];
    __syncthreads();
#pragma unroll
    for (int i = 0; i < 4; ++i)
        WT[(size_t)(n0 + ty + i * 8) * 1024 + k0 + tx] = f2bf(tile[tx][ty + i * 8]);
}

// ---------------- fused QKV projection GEMM (m97 structure) ----------------
__global__ __launch_bounds__(256)
void proj_gemm(const short* __restrict__ Xq, const short* __restrict__ Xk,
               const short* __restrict__ Xv,
               const short* __restrict__ WTq, const short* __restrict__ WTk,
               const short* __restrict__ WTv,
               const float* __restrict__ bq, const float* __restrict__ bk,
               const float* __restrict__ bv,
               short* __restrict__ QW, short* __restrict__ KW, short* __restrict__ VT) {
    __shared__ short As[128 * 64];
    __shared__ short Bs[128 * 64];
    const int tid = threadIdx.x;
    const int l = tid & 63, w = tid >> 6;
    const int g = l >> 4, ql = l & 15;
    const int m0 = blockIdx.x * 128, n0 = blockIdx.y * 128;
    const int z = blockIdx.z;
    const short* A  = (z == 0) ? Xq : (z == 1) ? Xk : Xv;
    const short* BT = (z == 0) ? WTq : (z == 1) ? WTk : WTv;
    const float* bias = (z == 0) ? bq : (z == 1) ? bk : bv;
    const int wr = w >> 1, wc = w & 1;

    v4f acc[4][4] = {};

    for (int kt = 0; kt < 16; ++kt) {
        const int kk = kt * 64;
        __syncthreads();
#pragma unroll
        for (int i = 0; i < 4; ++i) {
            int ci = i * 256 + tid;
            int row = ci >> 3, c = ci & 7;
            async16((char*)As + (size_t)(i * 256 + w * 64) * 16,
                    A + (size_t)(m0 + row) * 1024 + kk + c * 8);
            async16((char*)Bs + (size_t)(i * 256 + w * 64) * 16,
                    BT + (size_t)(n0 + row) * 1024 + kk + c * 8);
        }
        __syncthreads();
#pragma unroll
        for (int ks = 0; ks < 2; ++ks) {
            v8s af[4], bfr[4];
#pragma unroll
            for (int mt = 0; mt < 4; ++mt)
                af[mt] = *(const v8s*)(As + (wr * 64 + mt * 16 + ql) * 64 + ks * 32 + g * 8);
#pragma unroll
            for (int nt = 0; nt < 4; ++nt)
                bfr[nt] = *(const v8s*)(Bs + (wc * 64 + nt * 16 + ql) * 64 + ks * 32 + g * 8);
#pragma unroll
            for (int mt = 0; mt < 4; ++mt)
#pragma unroll
                for (int nt = 0; nt < 4; ++nt)
                    acc[mt][nt] = MFMA16(af[mt], bfr[nt], acc[mt][nt]);
        }
    }

#pragma unroll
    for (int nt = 0; nt < 4; ++nt) {
        int col = n0 + wc * 64 + nt * 16 + ql;
        float bval = bias[col];
        int hh = col >> 6, dd = col & 63;
#pragma unroll
        for (int mt = 0; mt < 4; ++mt) {
#pragma unroll
            for (int r = 0; r < 4; ++r) {
                int gm = m0 + wr * 64 + mt * 16 + g * 4 + r;
                int bb = gm >> 11, ss = gm & 2047;
                float vv = acc[mt][nt][r] + bval;
                if (z == 0) {
                    vv *= 0.125f * LOG2E;  // 1/sqrt(64) * log2e folded into Q
                    QW[((size_t)(bb * NH + hh) * S_LEN + ss) * 64 + dd] = f2bf(vv);
                } else if (z == 1) {
                    KW[((size_t)(bb * NH + hh) * S_LEN + ss) * 64 + dd] = f2bf(vv);
                } else {
                    VT[((size_t)(bb * NH + hh) * 64 + dd) * S_LEN + ss] = f2bf(vv);
                }
            }
        }
    }
}

// ---------------- flash attention (q-compacted, gload_lds staging) ----------
// Only q_mask=1 rows computed (others are zeroed by out_gemm's *q_mask).
// grid (64 bh, 9 chunks), chunk = 8-y (heaviest first -> greedy LPT balance;
// blocks with cy >= nq exit immediately). 4 waves x 32 compacted rows each;
// causal tiles bounded by the chunk's max ORIGINAL row index. Staging =
// global_load_lds with pre-swizzled source (rule #21). Penalty via 5th MFMA
// K-slice. Tree reductions + __shfl_xor cross-half. T13 defer-max.
__global__ __launch_bounds__(256, 4)
void attn_kernel(const short* __restrict__ QW, const short* __restrict__ KW,
                 const short* __restrict__ VT, const short* __restrict__ penC,
                 const int* __restrict__ idx, const int* __restrict__ nq,
                 short* __restrict__ O) {
    __shared__ short Ks[2][64 * 64];  // [kp][d], swizzled via source perm
    __shared__ short Vs[2][64 * 64];  // [d][kp], swizzled via source perm
    __shared__ int ntS;
    __shared__ int rflag;

    const int tid = threadIdx.x;
    const int l = tid & 63, w = tid >> 6;     // w in 0..3
    const int lq = l & 31, hi = l >> 5;
    const int bh = blockIdx.x;
    const int chunk = 8 - (int)blockIdx.y;    // heavy chunks dispatch first
    const int b = bh >> 4, hd = bh & 15;

    const int nqv = nq[b];
    const int cy = chunk * 128;               // compacted base row
    if (cy >= nqv) return;                    // empty chunk (uniform exit)

    const short* Qp = QW + (size_t)bh * S_LEN * 64;
    const short* Kp = KW + (size_t)bh * S_LEN * 64;
    const short* Vp = VT + (size_t)bh * 64 * S_LEN;
    const short* pp = penC + b * S_LEN;
    const int* idxb = idx + b * S_LEN;

    // this lane's compacted row j -> original row q_glob
    const int j = cy + w * 32 + lq;
    const bool jvalid = j < nqv;
    const int jj = jvalid ? j : (nqv - 1);
    const int q_glob = idxb[jj];
    const int qmin = __builtin_amdgcn_readfirstlane(q_glob);  // wave min row

    if (tid == 0) {
        int lastj = cy + 127; if (lastj > nqv - 1) lastj = nqv - 1;
        ntS = (idxb[lastj] >> 6) + 1;         // block causal tile count
    }

    // pre-swizzled gload_lds source coords (per-lane constants)
    const int srow = l >> 3;                // row within 8-row segment
    const int scol = (l & 7) ^ srow;        // XOR involution == read swz

    // Q fragments (B-operand of swapped QK^T): B[k=ks*16+hi*8+j][q=lq]
    v8s qf[4];
#pragma unroll
    for (int ks = 0; ks < 4; ++ks)
        qf[ks] = *(const v8s*)(Qp + (size_t)q_glob * 64 + ks * 16 + hi * 8);
    v8s qf4 = {};
    qf4[0] = hi ? (short)0 : (short)0x3F80;   // bf16(1.0) at virtual k=64

    v16f accO[2] = {};
    float m_run = -INFINITY, l_run = 0.f;

    auto stage = [&](int kt, int buf) {
        const int k0 = kt * 64;
#pragma unroll
        for (int i = 0; i < 2; ++i) {
            const int s = w * 2 + i;            // wave-uniform segment id
            const int row = s * 8 + srow;
            async16((char*)Ks[buf] + s * 1024,
                    Kp + (size_t)(k0 + row) * 64 + scol * 8);
            async16((char*)Vs[buf] + s * 1024,
                    Vp + (size_t)row * S_LEN + k0 + scol * 8);
        }
    };

    auto chalf = [&](int kt, int buf, bool causal, short p0, short p1) {
        const short* Kb = Ks[buf];
        const short* Vb = Vs[buf];

        // QK^T: acc[t] rows kp = t*32+(j&3)+8*(j>>2)+4*hi, col q = lq
        v16f acc0 = {}, acc1 = {};
        __builtin_amdgcn_s_setprio(1);
#pragma unroll
        for (int ks = 0; ks < 4; ++ks) {
            v8s k0f = *(const v8s*)((char*)Kb + swz(lq, ks * 32 + hi * 16));
            v8s k1f = *(const v8s*)((char*)Kb + swz(32 + lq, ks * 32 + hi * 16));
            acc0 = MFMA32(k0f, qf[ks], acc0);
            acc1 = MFMA32(k1f, qf[ks], acc1);
        }
        // 5th slice: v_mask penalty column (hi=0 lanes carry pen at k=64)
        v8s k4a = {}, k4b = {};
        k4a[0] = hi ? (short)0 : p0;
        k4b[0] = hi ? (short)0 : p1;
        acc0 = MFMA32(k4a, qf4, acc0);
        acc1 = MFMA32(k4b, qf4, acc1);
        __builtin_amdgcn_s_setprio(0);

        float s[32];
#pragma unroll
        for (int jn = 0; jn < 16; ++jn) { s[jn] = acc0[jn]; s[16 + jn] = acc1[jn]; }
        if (causal) {
#pragma unroll
            for (int t = 0; t < 2; ++t)
#pragma unroll
                for (int jn = 0; jn < 16; ++jn) {
                    int kp = kt * 64 + t * 32 + (jn & 3) + 8 * (jn >> 2) + 4 * hi;
                    if (kp > q_glob) s[t * 16 + jn] -= CMASK;
                }
        }
        // tree max (depth 5)
        float t8[8];
#pragma unroll
        for (int i = 0; i < 8; ++i)
            t8[i] = fmaxf(fmaxf(s[i], s[i + 8]), fmaxf(s[i + 16], s[i + 24]));
#pragma unroll
        for (int i = 0; i < 4; ++i) t8[i] = fmaxf(t8[i], t8[i + 4]);
        float tmax = fmaxf(fmaxf(t8[0], t8[1]), fmaxf(t8[2], t8[3]));
        tmax = fmaxf(tmax, __shfl_xor(tmax, 32, 64));   // cross-half

        // T13 defer-max: only rescale when max grew past threshold
        if (__any(tmax > m_run + DEFER_THR)) {
            float mnew = fmaxf(m_run, tmax);
            float scale = exp2f(m_run - mnew);
            m_run = mnew;
            l_run *= scale;
#pragma unroll
            for (int jn = 0; jn < 16; ++jn) {
                float sc = __shfl(scale, (jn & 3) + 8 * (jn >> 2) + 4 * hi, 64);
                accO[0][jn] *= sc;
                accO[1][jn] *= sc;
            }
        }
#pragma unroll
        for (int i = 0; i < 32; ++i) s[i] = exp2f(s[i] - m_run);
        // tree sum
        float u8[8];
#pragma unroll
        for (int i = 0; i < 8; ++i)
            u8[i] = (s[i] + s[i + 8]) + (s[i + 16] + s[i + 24]);
#pragma unroll
        for (int i = 0; i < 4; ++i) u8[i] += u8[i + 4];
        float psum = (u8[0] + u8[1]) + (u8[2] + u8[3]);
        psum += __shfl_xor(psum, 32, 64);               // cross-half
        l_run += psum;

        // P -> PV A-operand in registers (cvt_pk + permlane32_swap;
        // operands SSA-distinct -> no coalescing hazard)
        v8s PA[4];
#pragma unroll
        for (int t = 0; t < 2; ++t)
#pragma unroll
            for (int sf = 0; sf < 2; ++sf) {
                int base = t * 16 + sf * 8;
                unsigned x0 = cvtpk(s[base + 0], s[base + 1]);
                unsigned x1 = cvtpk(s[base + 2], s[base + 3]);
                unsigned y0 = cvtpk(s[base + 4], s[base + 5]);
                unsigned y1 = cvtpk(s[base + 6], s[base + 7]);
                asm volatile("v_permlane32_swap_b32 %0, %1" : "+v"(x0), "+v"(y0));
                asm volatile("v_permlane32_swap_b32 %0, %1" : "+v"(x1), "+v"(y1));
                v4u wv; wv[0] = x0; wv[1] = x1; wv[2] = y0; wv[3] = y1;
                union { v4u u; v8s s8; } cvt; cvt.u = wv;
                PA[t * 2 + sf] = cvt.s8;
            }

        // PV: A=P (in-reg), B=V[kp][d] via Vs=[d][kp]
        __builtin_amdgcn_s_setprio(1);
#pragma unroll
        for (int ks = 0; ks < 4; ++ks) {
            v8s v0f = *(const v8s*)((char*)Vb + swz(lq, ks * 32 + hi * 16));
            v8s v1f = *(const v8s*)((char*)Vb + swz(32 + lq, ks * 32 + hi * 16));
            accO[0] = MFMA32(PA[ks], v0f, accO[0]);
            accO[1] = MFMA32(PA[ks], v1f, accO[1]);
        }
        __builtin_amdgcn_s_setprio(0);
    };

    // main causal loop: gload_lds dbuf, ONE barrier per tile
    stage(0, 0);
    __syncthreads();                         // drains vmcnt; publishes ntS
    const int NT = ntS;
    for (int kt = 0; kt < NT; ++kt) {
        const int k0 = kt * 64;
        // pen loads FIRST (oldest in vmcnt) so their wait leaves prefetch in flight
        short p0 = pp[k0 + lq], p1 = pp[k0 + lq + 32];
        __builtin_amdgcn_sched_barrier(0);   // pin: pen loads before prefetch
        if (kt + 1 < NT) stage(kt + 1, (kt + 1) & 1);
        chalf(kt, kt & 1, k0 + 63 > qmin, p0, p1);
        __syncthreads();                     // drain prefetch + buffer reuse sync
    }

    // Rescue pass: rows whose causal-valid keys are ALL masked must tie with
    // future keys at exactly -CMASK (fp32 reference semantics).
    int kt = NT;
    while (kt < 32) {
        if (tid == 0) rflag = 0;
        __syncthreads();
        if (__any(m_run < -1e11f) && l == 0) rflag = 1;
        __syncthreads();
        if (!rflag) break;
        short p0 = pp[kt * 64 + lq], p1 = pp[kt * 64 + lq + 32];
        stage(kt, 0);
        __syncthreads();
        chalf(kt, 0, true, p0, p1);
        __syncthreads();
        ++kt;
    }

    // epilogue: rows q=(jn&3)+8*(jn>>2)+4*hi, cols d = dt*32+lq
    float inv = 1.0f / l_run;
#pragma unroll
    for (int jn = 0; jn < 16; ++jn) {
        int rowq = (jn & 3) + 8 * (jn >> 2) + 4 * hi;
        float iv = __shfl(inv, rowq, 64);
        int s_row = __shfl(q_glob, rowq, 64);          // original row index
        if (cy + w * 32 + rowq < nqv) {                // store only live rows
            size_t base = (size_t)(b * S_LEN + s_row) * 1024 + hd * 64 + lq;
            O[base]      = f2bf(accO[0][jn] * iv);
            O[base + 32] = f2bf(accO[1][jn] * iv);
        }
    }
}

// ---------------- output projection + bias + q_mask ----------------
__global__ __launch_bounds__(256)
void out_gemm(const short* __restrict__ A, const short* __restrict__ BT,
              const float* __restrict__ bias, const int* __restrict__ qmask,
              float* __restrict__ out) {
    __shared__ short As[128 * 64];
    __shared__ short Bs[128 * 64];
    const int tid = threadIdx.x;
    const int l = tid & 63, w = tid >> 6;
    const int g = l >> 4, ql = l & 15;
    const int m0 = blockIdx.x * 128, n0 = blockIdx.y * 128;
    const int wr = w >> 1, wc = w & 1;

    v4f acc[4][4] = {};

    for (int kt = 0; kt < 16; ++kt) {
        const int kk = kt * 64;
        __syncthreads();
#pragma unroll
        for (int i = 0; i < 4; ++i) {
            int ci = i * 256 + tid;
            int row = ci >> 3, c = ci & 7;
            async16((char*)As + (size_t)(i * 256 + w * 64) * 16,
                    A + (size_t)(m0 + row) * 1024 + kk + c * 8);
            async16((char*)Bs + (size_t)(i * 256 + w * 64) * 16,
                    BT + (size_t)(n0 + row) * 1024 + kk + c * 8);
        }
        __syncthreads();
#pragma unroll
        for (int ks = 0; ks < 2; ++ks) {
            v8s af[4], bfr[4];
#pragma unroll
            for (int mt = 0; mt < 4; ++mt)
                af[mt] = *(const v8s*)(As + (wr * 64 + mt * 16 + ql) * 64 + ks * 32 + g * 8);
#pragma unroll
            for (int nt = 0; nt < 4; ++nt)
                bfr[nt] = *(const v8s*)(Bs + (wc * 64 + nt * 16 + ql) * 64 + ks * 32 + g * 8);
#pragma unroll
            for (int mt = 0; mt < 4; ++mt)
#pragma unroll
                for (int nt = 0; nt < 4; ++nt)
                    acc[mt][nt] = MFMA16(af[mt], bfr[nt], acc[mt][nt]);
        }
    }

#pragma unroll
    for (int nt = 0; nt < 4; ++nt) {
        int col = n0 + wc * 64 + nt * 16 + ql;
        float bval = bias[col];
#pragma unroll
        for (int mt = 0; mt < 4; ++mt) {
#pragma unroll
            for (int r = 0; r < 4; ++r) {
                int gm = m0 + wr * 64 + mt * 16 + g * 4 + r;
                float vv = acc[mt][nt][r] + bval;
                vv *= (float)qmask[gm];
                out[(size_t)gm * 1024 + col] = vv;
            }
        }
    }
}

extern "C" void kernel_launch(void* const* d_in, const int* in_sizes, int n_in,
                              void* d_out, int out_size, void* d_ws, size_t ws_size,
                              hipStream_t stream) {
    (void)in_sizes; (void)n_in; (void)out_size; (void)ws_size;
    const float* q  = (const float*)d_in[0];
    const float* k  = (const float*)d_in[1];
    const float* v  = (const float*)d_in[2];
    const int* qmask = (const int*)d_in[3];
    const int* vmask = (const int*)d_in[4];
    const float* Wq = (const float*)d_in[5];
    const float* bq = (const float*)d_in[6];
    const float* Wk = (const float*)d_in[7];
    const float* bk = (const float*)d_in[8];
    const float* Wv = (const float*)d_in[9];
    const float* bv = (const float*)d_in[10];
    const float* Wo = (const float*)d_in[11];
    const float* bo = (const float*)d_in[12];
    float* out = (float*)d_out;

    char* ws = (char*)d_ws;
    const size_t MB = 1024 * 1024;
    short* Xq  = (short*)(ws + 0 * MB);
    short* Xk  = (short*)(ws + 16 * MB);
    short* Xv  = (short*)(ws + 32 * MB);
    short* WTq = (short*)(ws + 48 * MB);
    short* WTk = (short*)(ws + 50 * MB);
    short* WTv = (short*)(ws + 52 * MB);
    short* WTo = (short*)(ws + 54 * MB);
    short* QW  = (short*)(ws + 56 * MB);
    short* KW  = (short*)(ws + 72 * MB);
    short* VTb = (short*)(ws + 88 * MB);
    short* Ob  = (short*)(ws + 104 * MB);
    short* penC = (short*)(ws + 120 * MB);
    int* idxB  = (int*)(ws + 121 * MB);
    int* nqB   = (int*)(ws + 122 * MB);

    convert_f32_bf16<<<4096, 256, 0, stream>>>(q, Xq);
    convert_f32_bf16<<<4096, 256, 0, stream>>>(k, Xk);
    convert_f32_bf16<<<4096, 256, 0, stream>>>(v, Xv);
    transpose_w<<<dim3(32, 32), 256, 0, stream>>>(Wq, WTq);
    transpose_w<<<dim3(32, 32), 256, 0, stream>>>(Wk, WTk);
    transpose_w<<<dim3(32, 32), 256, 0, stream>>>(Wv, WTv);
    transpose_w<<<dim3(32, 32), 256, 0, stream>>>(Wo, WTo);
    build_pen<<<32, 256, 0, stream>>>(vmask, penC);
    compact_qmask<<<NB, 256, 0, stream>>>(qmask, idxB, nqB);

    proj_gemm<<<dim3(64, 8, 3), 256, 0, stream>>>(Xq, Xk, Xv, WTq, WTk, WTv,
                                                  bq, bk, bv, QW, KW, VTb);
    attn_kernel<<<dim3(64, 9), 256, 0, stream>>>(QW, KW, VTb, penC, idxB, nqB, Ob);
    out_gemm<<<dim3(64, 8), 256, 0, stream>>>(Ob, WTo, bo, qmask, out);
}

// Round 10
// 276.024 us; speedup vs baseline: 1.6589x; 1.0084x over previous
//
#include <hip/hip_runtime.h>
#include <hip/hip_bf16.h>

// ---- types ----
typedef __attribute__((ext_vector_type(8))) short v8s;   // 8 x bf16
typedef __attribute__((ext_vector_type(4))) float v4f;
typedef __attribute__((ext_vector_type(16))) float v16f; // 32x32 MFMA C/D
typedef __attribute__((ext_vector_type(4))) unsigned v4u;

#define S_LEN 2048
#define NB 4
#define NH 16
#define LOG2E 1.4426950408889634f
// Mask constant: 1.3125 * 2^40 — EXACTLY representable in bf16 AND fp32.
// Masked scores collapse to exactly -CMASK in fp32 (|s| << ulp/2 = 32768),
// so v_mask ties and causal ties stay bit-exact with each other.
#define CMASK 1443109011456.0f
#define DEFER_THR 11.55f                // ~8 * log2(e)  (T13)

__device__ __forceinline__ short f2bf(float f) {
    __hip_bfloat16 h = __float2bfloat16(f);
    union { __hip_bfloat16 h; short s; } u; u.h = h; return u.s;
}

__device__ __forceinline__ unsigned cvtpk(float lo, float hi) {
    unsigned r;
    asm("v_cvt_pk_bf16_f32 %0, %1, %2" : "=v"(r) : "v"(lo), "v"(hi));
    return r;
}

// XOR swizzle for [R][128B] LDS tiles (read side).
__device__ __forceinline__ int swz(int row, int col) {
    return (row * 128 + col) ^ ((row & 7) << 4);
}

__device__ __forceinline__ void async16(void* lds, const void* g) {
    __builtin_amdgcn_global_load_lds(
        (const __attribute__((address_space(1))) unsigned int*)g,
        (__attribute__((address_space(3))) unsigned int*)lds, 16, 0, 0);
}

#define MFMA16(a, b, c) __builtin_amdgcn_mfma_f32_16x16x32_bf16((a), (b), (c), 0, 0, 0)
#define MFMA32(a, b, c) __builtin_amdgcn_mfma_f32_32x32x16_bf16((a), (b), (c), 0, 0, 0)

// ---------------- convert fp32 -> bf16 (vectorized, G13) ----------------
__global__ __launch_bounds__(256) void convert_f32_bf16(const float* __restrict__ in,
                                                        short* __restrict__ out) {
    size_t i = ((size_t)blockIdx.x * 256 + threadIdx.x) * 8;
    float4 a = *(const float4*)(in + i);
    float4 b = *(const float4*)(in + i + 4);
    v8s o;
    o[0] = f2bf(a.x); o[1] = f2bf(a.y); o[2] = f2bf(a.z); o[3] = f2bf(a.w);
    o[4] = f2bf(b.x); o[5] = f2bf(b.y); o[6] = f2bf(b.z); o[7] = f2bf(b.w);
    *(v8s*)(out + i) = o;
}

// ---------------- penalty column: pen[b][s] = vm ? 0 : -CMASK (bf16) -------
__global__ __launch_bounds__(256) void build_pen(const int* __restrict__ vm,
                                                 short* __restrict__ penC) {
    int i = blockIdx.x * 256 + threadIdx.x;   // 8192 total
    penC[i] = vm[i] ? (short)0 : f2bf(-CMASK);
}

// ------------- q_mask compaction: idx[b][j] = j-th live row, nq[b] ---------
// out = (o@Wo+bo)*q_mask -> q_mask=0 rows are dead work in attention.
__global__ __launch_bounds__(256) void compact_qmask(const int* __restrict__ qm,
                                                     int* __restrict__ idx,
                                                     int* __restrict__ nq) {
    const int b = blockIdx.x;
    const int* m = qm + b * S_LEN;
    int* ib = idx + b * S_LEN;
    __shared__ int cnt[256];
    const int t = threadIdx.x;
    int loc[8], c = 0;
#pragma unroll
    for (int i = 0; i < 8; ++i) { int s = t * 8 + i; if (m[s]) loc[c++] = s; }
    cnt[t] = c;
    __syncthreads();
    for (int d = 1; d < 256; d <<= 1) {       // Hillis-Steele inclusive scan
        int v = (t >= d) ? cnt[t - d] : 0;
        __syncthreads();
        cnt[t] += v;
        __syncthreads();
    }
    int off = cnt[t] - c;                     // exclusive prefix
    for (int i = 0; i < c; ++i) ib[off + i] = loc[i];
    if (t == 255) nq[b] = cnt[255];
}

// ---------------- W[K][N] fp32 -> WT[N][K] bf16 ----------------
__global__ __launch_bounds__(256) void transpose_w(const float* __restrict__ W,
                                                   short* __restrict__ WT) {
    __shared__ float tile[32][33];
    int k0 = blockIdx.x * 32, n0 = blockIdx.y * 32;
    int tx = threadIdx.x & 31, ty = threadIdx.x >> 5;  // ty 0..7
#pragma unroll
    for (int i = 0; i < 4; ++i)
        tile[ty + i * 8][tx] = W[(size_t)(k0 + ty + i * 8) * 1024 + n0 + tx];
    __syncthreads();
#pragma unroll
    for (int i = 0; i < 4; ++i)
        WT[(size_t)(n0 + ty + i * 8) * 1024 + k0 + tx] = f2bf(tile[tx][ty + i * 8]);
}

// ---------------- fused QKV projection GEMM (m97 structure) ----------------
__global__ __launch_bounds__(256)
void proj_gemm(const short* __restrict__ Xq, const short* __restrict__ Xk,
               const short* __restrict__ Xv,
               const short* __restrict__ WTq, const short* __restrict__ WTk,
               const short* __restrict__ WTv,
               const float* __restrict__ bq, const float* __restrict__ bk,
               const float* __restrict__ bv,
               short* __restrict__ QW, short* __restrict__ KW, short* __restrict__ VT) {
    __shared__ short As[128 * 64];
    __shared__ short Bs[128 * 64];
    const int tid = threadIdx.x;
    const int l = tid & 63, w = tid >> 6;
    const int g = l >> 4, ql = l & 15;
    const int m0 = blockIdx.x * 128, n0 = blockIdx.y * 128;
    const int z = blockIdx.z;
    const short* A  = (z == 0) ? Xq : (z == 1) ? Xk : Xv;
    const short* BT = (z == 0) ? WTq : (z == 1) ? WTk : WTv;
    const float* bias = (z == 0) ? bq : (z == 1) ? bk : bv;
    const int wr = w >> 1, wc = w & 1;

    v4f acc[4][4] = {};

    for (int kt = 0; kt < 16; ++kt) {
        const int kk = kt * 64;
        __syncthreads();
#pragma unroll
        for (int i = 0; i < 4; ++i) {
            int ci = i * 256 + tid;
            int row = ci >> 3, c = ci & 7;
            async16((char*)As + (size_t)(i * 256 + w * 64) * 16,
                    A + (size_t)(m0 + row) * 1024 + kk + c * 8);
            async16((char*)Bs + (size_t)(i * 256 + w * 64) * 16,
                    BT + (size_t)(n0 + row) * 1024 + kk + c * 8);
        }
        __syncthreads();
#pragma unroll
        for (int ks = 0; ks < 2; ++ks) {
            v8s af[4], bfr[4];
#pragma unroll
            for (int mt = 0; mt < 4; ++mt)
                af[mt] = *(const v8s*)(As + (wr * 64 + mt * 16 + ql) * 64 + ks * 32 + g * 8);
#pragma unroll
            for (int nt = 0; nt < 4; ++nt)
                bfr[nt] = *(const v8s*)(Bs + (wc * 64 + nt * 16 + ql) * 64 + ks * 32 + g * 8);
#pragma unroll
            for (int mt = 0; mt < 4; ++mt)
#pragma unroll
                for (int nt = 0; nt < 4; ++nt)
                    acc[mt][nt] = MFMA16(af[mt], bfr[nt], acc[mt][nt]);
        }
    }

#pragma unroll
    for (int nt = 0; nt < 4; ++nt) {
        int col = n0 + wc * 64 + nt * 16 + ql;
        float bval = bias[col];
        int hh = col >> 6, dd = col & 63;
#pragma unroll
        for (int mt = 0; mt < 4; ++mt) {
#pragma unroll
            for (int r = 0; r < 4; ++r) {
                int gm = m0 + wr * 64 + mt * 16 + g * 4 + r;
                int bb = gm >> 11, ss = gm & 2047;
                float vv = acc[mt][nt][r] + bval;
                if (z == 0) {
                    vv *= 0.125f * LOG2E;  // 1/sqrt(64) * log2e folded into Q
                    QW[((size_t)(bb * NH + hh) * S_LEN + ss) * 64 + dd] = f2bf(vv);
                } else if (z == 1) {
                    KW[((size_t)(bb * NH + hh) * S_LEN + ss) * 64 + dd] = f2bf(vv);
                } else {
                    VT[((size_t)(bb * NH + hh) * 64 + dd) * S_LEN + ss] = f2bf(vv);
                }
            }
        }
    }
}

// ---------------- flash attention (q-compacted, counted-vmcnt pipeline) -----
// R9 issue: __syncthreads() per tile drains vmcnt(0) -> every tile waits for
// the NEXT tile's prefetch (m97-ceiling stall). Fix = m201/T3+T4 pattern:
// 3 LDS buffers, depth-2 prefetch, raw s_barrier + counted s_waitcnt vmcnt(4)
// (never 0 in-loop). Buffer (kt+2)%3 staged at tile kt was last read at tile
// kt-1; the top-of-kt barrier proves all waves passed it -> race-free.
// Pen row staged to LDS once (lgkm-only reads keep the vmcnt ledger exact:
// 4 loads/wave/tile).
__global__ __launch_bounds__(256, 4)
void attn_kernel(const short* __restrict__ QW, const short* __restrict__ KW,
                 const short* __restrict__ VT, const short* __restrict__ penC,
                 const int* __restrict__ idx, const int* __restrict__ nq,
                 short* __restrict__ O) {
    __shared__ short Ks[3][64 * 64];  // [kp][d], swizzled via source perm
    __shared__ short Vs[3][64 * 64];  // [d][kp], swizzled via source perm
    __shared__ short penS[S_LEN];     // per-key penalty (bf16), whole batch row
    __shared__ int rflag;

    const int tid = threadIdx.x;
    const int l = tid & 63, w = tid >> 6;     // w in 0..3
    const int lq = l & 31, hi = l >> 5;
    const int bh = blockIdx.x;
    const int chunk = 8 - (int)blockIdx.y;    // heavy chunks dispatch first
    const int b = bh >> 4, hd = bh & 15;

    const int nqv = nq[b];
    const int cy = chunk * 128;               // compacted base row
    if (cy >= nqv) return;                    // empty chunk (uniform exit)

    const short* Qp = QW + (size_t)bh * S_LEN * 64;
    const short* Kp = KW + (size_t)bh * S_LEN * 64;
    const short* Vp = VT + (size_t)bh * 64 * S_LEN;
    const short* pp = penC + b * S_LEN;
    const int* idxb = idx + b * S_LEN;

    // this lane's compacted row j -> original row q_glob
    const int j = cy + w * 32 + lq;
    const bool jvalid = j < nqv;
    const int jj = jvalid ? j : (nqv - 1);
    const int q_glob = idxb[jj];
    const int qmin = __builtin_amdgcn_readfirstlane(q_glob);  // wave min row

    // block causal tile count (uniform: all threads load the same element)
    int lastj = cy + 127; if (lastj > nqv - 1) lastj = nqv - 1;
    const int NT = (idxb[lastj] >> 6) + 1;

    // pre-swizzled gload_lds source coords (per-lane constants)
    const int srow = l >> 3;                // row within 8-row segment
    const int scol = (l & 7) ^ srow;        // XOR involution == read swz

    // Q fragments (B-operand of swapped QK^T): B[k=ks*16+hi*8+j][q=lq]
    v8s qf[4];
#pragma unroll
    for (int ks = 0; ks < 4; ++ks)
        qf[ks] = *(const v8s*)(Qp + (size_t)q_glob * 64 + ks * 16 + hi * 8);
    v8s qf4 = {};
    qf4[0] = hi ? (short)0 : (short)0x3F80;   // bf16(1.0) at virtual k=64

    v16f accO[2] = {};
    float m_run = -INFINITY, l_run = 0.f;

    auto stage = [&](int kt, int buf) {
        const int k0 = kt * 64;
#pragma unroll
        for (int i = 0; i < 2; ++i) {
            const int s = w * 2 + i;            // wave-uniform segment id
            const int row = s * 8 + srow;
            async16((char*)Ks[buf] + s * 1024,
                    Kp + (size_t)(k0 + row) * 64 + scol * 8);
            async16((char*)Vs[buf] + s * 1024,
                    Vp + (size_t)row * S_LEN + k0 + scol * 8);
        }
    };

    auto chalf = [&](int kt, int buf, bool causal, short p0, short p1) {
        const short* Kb = Ks[buf];
        const short* Vb = Vs[buf];

        // QK^T: acc[t] rows kp = t*32+(j&3)+8*(j>>2)+4*hi, col q = lq
        v16f acc0 = {}, acc1 = {};
        __builtin_amdgcn_s_setprio(1);
#pragma unroll
        for (int ks = 0; ks < 4; ++ks) {
            v8s k0f = *(const v8s*)((char*)Kb + swz(lq, ks * 32 + hi * 16));
            v8s k1f = *(const v8s*)((char*)Kb + swz(32 + lq, ks * 32 + hi * 16));
            acc0 = MFMA32(k0f, qf[ks], acc0);
            acc1 = MFMA32(k1f, qf[ks], acc1);
        }
        // 5th slice: v_mask penalty column (hi=0 lanes carry pen at k=64)
        v8s k4a = {}, k4b = {};
        k4a[0] = hi ? (short)0 : p0;
        k4b[0] = hi ? (short)0 : p1;
        acc0 = MFMA32(k4a, qf4, acc0);
        acc1 = MFMA32(k4b, qf4, acc1);
        __builtin_amdgcn_s_setprio(0);

        float s[32];
#pragma unroll
        for (int jn = 0; jn < 16; ++jn) { s[jn] = acc0[jn]; s[16 + jn] = acc1[jn]; }
        if (causal) {
#pragma unroll
            for (int t = 0; t < 2; ++t)
#pragma unroll
                for (int jn = 0; jn < 16; ++jn) {
                    int kp = kt * 64 + t * 32 + (jn & 3) + 8 * (jn >> 2) + 4 * hi;
                    if (kp > q_glob) s[t * 16 + jn] -= CMASK;
                }
        }
        // tree max (depth 5)
        float t8[8];
#pragma unroll
        for (int i = 0; i < 8; ++i)
            t8[i] = fmaxf(fmaxf(s[i], s[i + 8]), fmaxf(s[i + 16], s[i + 24]));
#pragma unroll
        for (int i = 0; i < 4; ++i) t8[i] = fmaxf(t8[i], t8[i + 4]);
        float tmax = fmaxf(fmaxf(t8[0], t8[1]), fmaxf(t8[2], t8[3]));
        tmax = fmaxf(tmax, __shfl_xor(tmax, 32, 64));   // cross-half

        // T13 defer-max: only rescale when max grew past threshold
        if (__any(tmax > m_run + DEFER_THR)) {
            float mnew = fmaxf(m_run, tmax);
            float scale = exp2f(m_run - mnew);
            m_run = mnew;
            l_run *= scale;
#pragma unroll
            for (int jn = 0; jn < 16; ++jn) {
                float sc = __shfl(scale, (jn & 3) + 8 * (jn >> 2) + 4 * hi, 64);
                accO[0][jn] *= sc;
                accO[1][jn] *= sc;
            }
        }
#pragma unroll
        for (int i = 0; i < 32; ++i) s[i] = exp2f(s[i] - m_run);
        // tree sum
        float u8[8];
#pragma unroll
        for (int i = 0; i < 8; ++i)
            u8[i] = (s[i] + s[i + 8]) + (s[i + 16] + s[i + 24]);
#pragma unroll
        for (int i = 0; i < 4; ++i) u8[i] += u8[i + 4];
        float psum = (u8[0] + u8[1]) + (u8[2] + u8[3]);
        psum += __shfl_xor(psum, 32, 64);               // cross-half
        l_run += psum;

        // P -> PV A-operand in registers (cvt_pk + permlane32_swap;
        // operands SSA-distinct -> no coalescing hazard)
        v8s PA[4];
#pragma unroll
        for (int t = 0; t < 2; ++t)
#pragma unroll
            for (int sf = 0; sf < 2; ++sf) {
                int base = t * 16 + sf * 8;
                unsigned x0 = cvtpk(s[base + 0], s[base + 1]);
                unsigned x1 = cvtpk(s[base + 2], s[base + 3]);
                unsigned y0 = cvtpk(s[base + 4], s[base + 5]);
                unsigned y1 = cvtpk(s[base + 6], s[base + 7]);
                asm volatile("v_permlane32_swap_b32 %0, %1" : "+v"(x0), "+v"(y0));
                asm volatile("v_permlane32_swap_b32 %0, %1" : "+v"(x1), "+v"(y1));
                v4u wv; wv[0] = x0; wv[1] = x1; wv[2] = y0; wv[3] = y1;
                union { v4u u; v8s s8; } cvt; cvt.u = wv;
                PA[t * 2 + sf] = cvt.s8;
            }

        // PV: A=P (in-reg), B=V[kp][d] via Vs=[d][kp]
        __builtin_amdgcn_s_setprio(1);
#pragma unroll
        for (int ks = 0; ks < 4; ++ks) {
            v8s v0f = *(const v8s*)((char*)Vb + swz(lq, ks * 32 + hi * 16));
            v8s v1f = *(const v8s*)((char*)Vb + swz(32 + lq, ks * 32 + hi * 16));
            accO[0] = MFMA32(PA[ks], v0f, accO[0]);
            accO[1] = MFMA32(PA[ks], v1f, accO[1]);
        }
        __builtin_amdgcn_s_setprio(0);
    };

    // ---- prologue: clean VMEM slate, then pen + depth-2 prefetch ----
    asm volatile("s_waitcnt vmcnt(0)" ::: "memory");
    asm volatile("" : : "v"(qf[0]), "v"(qf[1]), "v"(qf[2]), "v"(qf[3]));
    async16((char*)penS + w * 1024, pp + w * 512 + l * 8);  // 4KB pen row
    stage(0, 0);
    stage(1, 1);                              // NT >= 4 always (chunk 0 -> 4)

    // ---- main loop: counted vmcnt + raw barrier (ONE per tile) ----
    for (int kt = 0; kt < NT; ++kt) {
        const int k0 = kt * 64;
        if (kt + 1 < NT) asm volatile("s_waitcnt vmcnt(4)" ::: "memory");
        else             asm volatile("s_waitcnt vmcnt(0)" ::: "memory");
        __builtin_amdgcn_sched_barrier(0);
        __builtin_amdgcn_s_barrier();
        __builtin_amdgcn_sched_barrier(0);    // rule #18: no ds_read hoisting
        if (kt + 2 < NT) stage(kt + 2, (kt + 2) % 3);
        short p0 = penS[k0 + lq], p1 = penS[k0 + lq + 32];
        chalf(kt, kt % 3, k0 + 63 > qmin, p0, p1);
    }

    // Rescue pass: rows whose causal-valid keys are ALL masked must tie with
    // future keys at exactly -CMASK (fp32 reference semantics). vmcnt is 0
    // here (last iter waited 0); plain __syncthreads path, rare.
    int kt = NT;
    while (kt < 32) {
        if (tid == 0) rflag = 0;
        __syncthreads();
        if (__any(m_run < -1e11f) && l == 0) rflag = 1;
        __syncthreads();
        if (!rflag) break;
        short p0 = penS[kt * 64 + lq], p1 = penS[kt * 64 + lq + 32];
        stage(kt, 0);
        __syncthreads();
        chalf(kt, 0, true, p0, p1);
        __syncthreads();
        ++kt;
    }

    // epilogue: rows q=(jn&3)+8*(jn>>2)+4*hi, cols d = dt*32+lq
    float inv = 1.0f / l_run;
#pragma unroll
    for (int jn = 0; jn < 16; ++jn) {
        int rowq = (jn & 3) + 8 * (jn >> 2) + 4 * hi;
        float iv = __shfl(inv, rowq, 64);
        int s_row = __shfl(q_glob, rowq, 64);          // original row index
        if (cy + w * 32 + rowq < nqv) {                // store only live rows
            size_t base = (size_t)(b * S_LEN + s_row) * 1024 + hd * 64 + lq;
            O[base]      = f2bf(accO[0][jn] * iv);
            O[base + 32] = f2bf(accO[1][jn] * iv);
        }
    }
}

// ---------------- output projection + bias + q_mask ----------------
__global__ __launch_bounds__(256)
void out_gemm(const short* __restrict__ A, const short* __restrict__ BT,
              const float* __restrict__ bias, const int* __restrict__ qmask,
              float* __restrict__ out) {
    __shared__ short As[128 * 64];
    __shared__ short Bs[128 * 64];
    const int tid = threadIdx.x;
    const int l = tid & 63, w = tid >> 6;
    const int g = l >> 4, ql = l & 15;
    const int m0 = blockIdx.x * 128, n0 = blockIdx.y * 128;
    const int wr = w >> 1, wc = w & 1;

    v4f acc[4][4] = {};

    for (int kt = 0; kt < 16; ++kt) {
        const int kk = kt * 64;
        __syncthreads();
#pragma unroll
        for (int i = 0; i < 4; ++i) {
            int ci = i * 256 + tid;
            int row = ci >> 3, c = ci & 7;
            async16((char*)As + (size_t)(i * 256 + w * 64) * 16,
                    A + (size_t)(m0 + row) * 1024 + kk + c * 8);
            async16((char*)Bs + (size_t)(i * 256 + w * 64) * 16,
                    BT + (size_t)(n0 + row) * 1024 + kk + c * 8);
        }
        __syncthreads();
#pragma unroll
        for (int ks = 0; ks < 2; ++ks) {
            v8s af[4], bfr[4];
#pragma unroll
            for (int mt = 0; mt < 4; ++mt)
                af[mt] = *(const v8s*)(As + (wr * 64 + mt * 16 + ql) * 64 + ks * 32 + g * 8);
#pragma unroll
            for (int nt = 0; nt < 4; ++nt)
                bfr[nt] = *(const v8s*)(Bs + (wc * 64 + nt * 16 + ql) * 64 + ks * 32 + g * 8);
#pragma unroll
            for (int mt = 0; mt < 4; ++mt)
#pragma unroll
                for (int nt = 0; nt < 4; ++nt)
                    acc[mt][nt] = MFMA16(af[mt], bfr[nt], acc[mt][nt]);
        }
    }

#pragma unroll
    for (int nt = 0; nt < 4; ++nt) {
        int col = n0 + wc * 64 + nt * 16 + ql;
        float bval = bias[col];
#pragma unroll
        for (int mt = 0; mt < 4; ++mt) {
#pragma unroll
            for (int r = 0; r < 4; ++r) {
                int gm = m0 + wr * 64 + mt * 16 + g * 4 + r;
                float vv = acc[mt][nt][r] + bval;
                vv *= (float)qmask[gm];
                out[(size_t)gm * 1024 + col] = vv;
            }
        }
    }
}

extern "C" void kernel_launch(void* const* d_in, const int* in_sizes, int n_in,
                              void* d_out, int out_size, void* d_ws, size_t ws_size,
                              hipStream_t stream) {
    (void)in_sizes; (void)n_in; (void)out_size; (void)ws_size;
    const float* q  = (const float*)d_in[0];
    const float* k  = (const float*)d_in[1];
    const float* v  = (const float*)d_in[2];
    const int* qmask = (const int*)d_in[3];
    const int* vmask = (const int*)d_in[4];
    const float* Wq = (const float*)d_in[5];
    const float* bq = (const float*)d_in[6];
    const float* Wk = (const float*)d_in[7];
    const float* bk = (const float*)d_in[8];
    const float* Wv = (const float*)d_in[9];
    const float* bv = (const float*)d_in[10];
    const float* Wo = (const float*)d_in[11];
    const float* bo = (const float*)d_in[12];
    float* out = (float*)d_out;

    char* ws = (char*)d_ws;
    const size_t MB = 1024 * 1024;
    short* Xq  = (short*)(ws + 0 * MB);
    short* Xk  = (short*)(ws + 16 * MB);
    short* Xv  = (short*)(ws + 32 * MB);
    short* WTq = (short*)(ws + 48 * MB);
    short* WTk = (short*)(ws + 50 * MB);
    short* WTv = (short*)(ws + 52 * MB);
    short* WTo = (short*)(ws + 54 * MB);
    short* QW  = (short*)(ws + 56 * MB);
    short* KW  = (short*)(ws + 72 * MB);
    short* VTb = (short*)(ws + 88 * MB);
    short* Ob  = (short*)(ws + 104 * MB);
    short* penC = (short*)(ws + 120 * MB);
    int* idxB  = (int*)(ws + 121 * MB);
    int* nqB   = (int*)(ws + 122 * MB);

    convert_f32_bf16<<<4096, 256, 0, stream>>>(q, Xq);
    convert_f32_bf16<<<4096, 256, 0, stream>>>(k, Xk);
    convert_f32_bf16<<<4096, 256, 0, stream>>>(v, Xv);
    transpose_w<<<dim3(32, 32), 256, 0, stream>>>(Wq, WTq);
    transpose_w<<<dim3(32, 32), 256, 0, stream>>>(Wk, WTk);
    transpose_w<<<dim3(32, 32), 256, 0, stream>>>(Wv, WTv);
    transpose_w<<<dim3(32, 32), 256, 0, stream>>>(Wo, WTo);
    build_pen<<<32, 256, 0, stream>>>(vmask, penC);
    compact_qmask<<<NB, 256, 0, stream>>>(qmask, idxB, nqB);

    proj_gemm<<<dim3(64, 8, 3), 256, 0, stream>>>(Xq, Xk, Xv, WTq, WTk, WTv,
                                                  bq, bk, bv, QW, KW, VTb);
    attn_kernel<<<dim3(64, 9), 256, 0, stream>>>(QW, KW, VTb, penC, idxB, nqB, Ob);
    out_gemm<<<dim3(64, 8), 256, 0, stream>>>(Ob, WTo, bo, qmask, out);
}

// Round 11
// 275.297 us; speedup vs baseline: 1.6633x; 1.0026x over previous
//
#include <hip/hip_runtime.h>
#include <hip/hip_bf16.h>

// ---- types ----
typedef __attribute__((ext_vector_type(8))) short v8s;   // 8 x bf16
typedef __attribute__((ext_vector_type(4))) float v4f;
typedef __attribute__((ext_vector_type(16))) float v16f; // 32x32 MFMA C/D
typedef __attribute__((ext_vector_type(4))) unsigned v4u;

#define S_LEN 2048
#define NB 4
#define NH 16
#define LOG2E 1.4426950408889634f
// Mask constant: 1.3125 * 2^40 — EXACTLY representable in bf16 AND fp32.
// Masked scores collapse to exactly -CMASK in fp32 (|s| << ulp/2 = 32768),
// so v_mask ties and causal ties stay bit-exact with each other.
#define CMASK 1443109011456.0f
#define DEFER_THR 11.55f                // ~8 * log2(e)  (T13)

__device__ __forceinline__ short f2bf(float f) {
    __hip_bfloat16 h = __float2bfloat16(f);
    union { __hip_bfloat16 h; short s; } u; u.h = h; return u.s;
}

__device__ __forceinline__ unsigned cvtpk(float lo, float hi) {
    unsigned r;
    asm("v_cvt_pk_bf16_f32 %0, %1, %2" : "=v"(r) : "v"(lo), "v"(hi));
    return r;
}

// XOR swizzle for [R][128B] LDS tiles (read side).
__device__ __forceinline__ int swz(int row, int col) {
    return (row * 128 + col) ^ ((row & 7) << 4);
}

__device__ __forceinline__ void async16(void* lds, const void* g) {
    __builtin_amdgcn_global_load_lds(
        (const __attribute__((address_space(1))) unsigned int*)g,
        (__attribute__((address_space(3))) unsigned int*)lds, 16, 0, 0);
}

#define MFMA16(a, b, c) __builtin_amdgcn_mfma_f32_16x16x32_bf16((a), (b), (c), 0, 0, 0)
#define MFMA32(a, b, c) __builtin_amdgcn_mfma_f32_32x32x16_bf16((a), (b), (c), 0, 0, 0)

// ---------------- convert fp32 -> bf16 (vectorized, G13) ----------------
__global__ __launch_bounds__(256) void convert_f32_bf16(const float* __restrict__ in,
                                                        short* __restrict__ out) {
    size_t i = ((size_t)blockIdx.x * 256 + threadIdx.x) * 8;
    float4 a = *(const float4*)(in + i);
    float4 b = *(const float4*)(in + i + 4);
    v8s o;
    o[0] = f2bf(a.x); o[1] = f2bf(a.y); o[2] = f2bf(a.z); o[3] = f2bf(a.w);
    o[4] = f2bf(b.x); o[5] = f2bf(b.y); o[6] = f2bf(b.z); o[7] = f2bf(b.w);
    *(v8s*)(out + i) = o;
}

// ---------------- penalty column: pen[b][s] = vm ? 0 : -CMASK (bf16) -------
__global__ __launch_bounds__(256) void build_pen(const int* __restrict__ vm,
                                                 short* __restrict__ penC) {
    int i = blockIdx.x * 256 + threadIdx.x;   // 8192 total
    penC[i] = vm[i] ? (short)0 : f2bf(-CMASK);
}

// ------------- q_mask compaction: idx[b][j] = j-th live row, nq[b] ---------
// out = (o@Wo+bo)*q_mask -> q_mask=0 rows are dead work in attention.
__global__ __launch_bounds__(256) void compact_qmask(const int* __restrict__ qm,
                                                     int* __restrict__ idx,
                                                     int* __restrict__ nq) {
    const int b = blockIdx.x;
    const int* m = qm + b * S_LEN;
    int* ib = idx + b * S_LEN;
    __shared__ int cnt[256];
    const int t = threadIdx.x;
    int loc[8], c = 0;
#pragma unroll
    for (int i = 0; i < 8; ++i) { int s = t * 8 + i; if (m[s]) loc[c++] = s; }
    cnt[t] = c;
    __syncthreads();
    for (int d = 1; d < 256; d <<= 1) {       // Hillis-Steele inclusive scan
        int v = (t >= d) ? cnt[t - d] : 0;
        __syncthreads();
        cnt[t] += v;
        __syncthreads();
    }
    int off = cnt[t] - c;                     // exclusive prefix
    for (int i = 0; i < c; ++i) ib[off + i] = loc[i];
    if (t == 255) nq[b] = cnt[255];
}

// ---------------- W[K][N] fp32 -> WT[N][K] bf16 ----------------
__global__ __launch_bounds__(256) void transpose_w(const float* __restrict__ W,
                                                   short* __restrict__ WT) {
    __shared__ float tile[32][33];
    int k0 = blockIdx.x * 32, n0 = blockIdx.y * 32;
    int tx = threadIdx.x & 31, ty = threadIdx.x >> 5;  // ty 0..7
#pragma unroll
    for (int i = 0; i < 4; ++i)
        tile[ty + i * 8][tx] = W[(size_t)(k0 + ty + i * 8) * 1024 + n0 + tx];
    __syncthreads();
#pragma unroll
    for (int i = 0; i < 4; ++i)
        WT[(size_t)(n0 + ty + i * 8) * 1024 + k0 + tx] = f2bf(tile[tx][ty + i * 8]);
}

// ---------------- fused QKV projection GEMM (m97 structure) ----------------
__global__ __launch_bounds__(256)
void proj_gemm(const short* __restrict__ Xq, const short* __restrict__ Xk,
               const short* __restrict__ Xv,
               const short* __restrict__ WTq, const short* __restrict__ WTk,
               const short* __restrict__ WTv,
               const float* __restrict__ bq, const float* __restrict__ bk,
               const float* __restrict__ bv,
               short* __restrict__ QW, short* __restrict__ KW, short* __restrict__ VT) {
    __shared__ short As[128 * 64];
    __shared__ short Bs[128 * 64];
    const int tid = threadIdx.x;
    const int l = tid & 63, w = tid >> 6;
    const int g = l >> 4, ql = l & 15;
    const int m0 = blockIdx.x * 128, n0 = blockIdx.y * 128;
    const int z = blockIdx.z;
    const short* A  = (z == 0) ? Xq : (z == 1) ? Xk : Xv;
    const short* BT = (z == 0) ? WTq : (z == 1) ? WTk : WTv;
    const float* bias = (z == 0) ? bq : (z == 1) ? bk : bv;
    const int wr = w >> 1, wc = w & 1;

    v4f acc[4][4] = {};

    for (int kt = 0; kt < 16; ++kt) {
        const int kk = kt * 64;
        __syncthreads();
#pragma unroll
        for (int i = 0; i < 4; ++i) {
            int ci = i * 256 + tid;
            int row = ci >> 3, c = ci & 7;
            async16((char*)As + (size_t)(i * 256 + w * 64) * 16,
                    A + (size_t)(m0 + row) * 1024 + kk + c * 8);
            async16((char*)Bs + (size_t)(i * 256 + w * 64) * 16,
                    BT + (size_t)(n0 + row) * 1024 + kk + c * 8);
        }
        __syncthreads();
#pragma unroll
        for (int ks = 0; ks < 2; ++ks) {
            v8s af[4], bfr[4];
#pragma unroll
            for (int mt = 0; mt < 4; ++mt)
                af[mt] = *(const v8s*)(As + (wr * 64 + mt * 16 + ql) * 64 + ks * 32 + g * 8);
#pragma unroll
            for (int nt = 0; nt < 4; ++nt)
                bfr[nt] = *(const v8s*)(Bs + (wc * 64 + nt * 16 + ql) * 64 + ks * 32 + g * 8);
#pragma unroll
            for (int mt = 0; mt < 4; ++mt)
#pragma unroll
                for (int nt = 0; nt < 4; ++nt)
                    acc[mt][nt] = MFMA16(af[mt], bfr[nt], acc[mt][nt]);
        }
    }

#pragma unroll
    for (int nt = 0; nt < 4; ++nt) {
        int col = n0 + wc * 64 + nt * 16 + ql;
        float bval = bias[col];
        int hh = col >> 6, dd = col & 63;
#pragma unroll
        for (int mt = 0; mt < 4; ++mt) {
#pragma unroll
            for (int r = 0; r < 4; ++r) {
                int gm = m0 + wr * 64 + mt * 16 + g * 4 + r;
                int bb = gm >> 11, ss = gm & 2047;
                float vv = acc[mt][nt][r] + bval;
                if (z == 0) {
                    vv *= 0.125f * LOG2E;  // 1/sqrt(64) * log2e folded into Q
                    QW[((size_t)(bb * NH + hh) * S_LEN + ss) * 64 + dd] = f2bf(vv);
                } else if (z == 1) {
                    KW[((size_t)(bb * NH + hh) * S_LEN + ss) * 64 + dd] = f2bf(vv);
                } else {
                    VT[((size_t)(bb * NH + hh) * 64 + dd) * S_LEN + ss] = f2bf(vv);
                }
            }
        }
    }
}

// ---------------- flash attention (TLP-first: 2-wave blocks, 64 q-rows) -----
// R10 counters: Occupancy 11.4% ~= 0.9 waves/SIMD -> pure latency-bound; grid
// (576 blocks) was the binding constraint, not the schedule. Repartition:
// 2-wave blocks (128 thr) x 64 compacted q-rows -> ~1100 live blocks
// (~4.3/CU x 2 waves ~= 2+ waves/SIMD). LDS trimmed to 2 buffers + penS
// (36.5KB, 4 blocks/CU fit). Counted-vmcnt depth-1 prefetch kept (free).
__global__ __launch_bounds__(128, 4)
void attn_kernel(const short* __restrict__ QW, const short* __restrict__ KW,
                 const short* __restrict__ VT, const short* __restrict__ penC,
                 const int* __restrict__ idx, const int* __restrict__ nq,
                 short* __restrict__ O) {
    __shared__ short Ks[2][64 * 64];  // [kp][d], swizzled via source perm
    __shared__ short Vs[2][64 * 64];  // [d][kp], swizzled via source perm
    __shared__ short penS[S_LEN];     // per-key penalty (bf16), whole batch row
    __shared__ int rflag;

    const int tid = threadIdx.x;
    const int l = tid & 63, w = tid >> 6;     // w in 0..1
    const int lq = l & 31, hi = l >> 5;
    const int bh = blockIdx.x;
    const int chunk = 31 - (int)blockIdx.y;   // heavy chunks dispatch first
    const int b = bh >> 4, hd = bh & 15;

    const int nqv = nq[b];
    const int cy = chunk * 64;                // compacted base row
    if (cy >= nqv) return;                    // empty chunk (uniform exit)

    const short* Qp = QW + (size_t)bh * S_LEN * 64;
    const short* Kp = KW + (size_t)bh * S_LEN * 64;
    const short* Vp = VT + (size_t)bh * 64 * S_LEN;
    const short* pp = penC + b * S_LEN;
    const int* idxb = idx + b * S_LEN;

    // this lane's compacted row j -> original row q_glob
    const int j = cy + w * 32 + lq;
    const bool jvalid = j < nqv;
    const int jj = jvalid ? j : (nqv - 1);
    const int q_glob = idxb[jj];
    const int qmin = __builtin_amdgcn_readfirstlane(q_glob);  // wave min row

    // block causal tile count (uniform: all threads load the same element)
    int lastj = cy + 63; if (lastj > nqv - 1) lastj = nqv - 1;
    const int NT = (idxb[lastj] >> 6) + 1;

    // pre-swizzled gload_lds source coords (per-lane constants)
    const int srow = l >> 3;                // row within 8-row segment
    const int scol = (l & 7) ^ srow;        // XOR involution == read swz

    // Q fragments (B-operand of swapped QK^T): B[k=ks*16+hi*8+j][q=lq]
    v8s qf[4];
#pragma unroll
    for (int ks = 0; ks < 4; ++ks)
        qf[ks] = *(const v8s*)(Qp + (size_t)q_glob * 64 + ks * 16 + hi * 8);
    v8s qf4 = {};
    qf4[0] = hi ? (short)0 : (short)0x3F80;   // bf16(1.0) at virtual k=64

    v16f accO[2] = {};
    float m_run = -INFINITY, l_run = 0.f;

    auto stage = [&](int kt, int buf) {
        const int k0 = kt * 64;
#pragma unroll
        for (int i = 0; i < 4; ++i) {
            const int s = w * 4 + i;            // wave-uniform segment id (0..7)
            const int row = s * 8 + srow;
            async16((char*)Ks[buf] + s * 1024,
                    Kp + (size_t)(k0 + row) * 64 + scol * 8);
            async16((char*)Vs[buf] + s * 1024,
                    Vp + (size_t)row * S_LEN + k0 + scol * 8);
        }
    };

    auto chalf = [&](int kt, int buf, bool causal, short p0, short p1) {
        const short* Kb = Ks[buf];
        const short* Vb = Vs[buf];

        // QK^T: acc[t] rows kp = t*32+(j&3)+8*(j>>2)+4*hi, col q = lq
        v16f acc0 = {}, acc1 = {};
        __builtin_amdgcn_s_setprio(1);
#pragma unroll
        for (int ks = 0; ks < 4; ++ks) {
            v8s k0f = *(const v8s*)((char*)Kb + swz(lq, ks * 32 + hi * 16));
            v8s k1f = *(const v8s*)((char*)Kb + swz(32 + lq, ks * 32 + hi * 16));
            acc0 = MFMA32(k0f, qf[ks], acc0);
            acc1 = MFMA32(k1f, qf[ks], acc1);
        }
        // 5th slice: v_mask penalty column (hi=0 lanes carry pen at k=64)
        v8s k4a = {}, k4b = {};
        k4a[0] = hi ? (short)0 : p0;
        k4b[0] = hi ? (short)0 : p1;
        acc0 = MFMA32(k4a, qf4, acc0);
        acc1 = MFMA32(k4b, qf4, acc1);
        __builtin_amdgcn_s_setprio(0);

        float s[32];
#pragma unroll
        for (int jn = 0; jn < 16; ++jn) { s[jn] = acc0[jn]; s[16 + jn] = acc1[jn]; }
        if (causal) {
#pragma unroll
            for (int t = 0; t < 2; ++t)
#pragma unroll
                for (int jn = 0; jn < 16; ++jn) {
                    int kp = kt * 64 + t * 32 + (jn & 3) + 8 * (jn >> 2) + 4 * hi;
                    if (kp > q_glob) s[t * 16 + jn] -= CMASK;
                }
        }
        // tree max (depth 5)
        float t8[8];
#pragma unroll
        for (int i = 0; i < 8; ++i)
            t8[i] = fmaxf(fmaxf(s[i], s[i + 8]), fmaxf(s[i + 16], s[i + 24]));
#pragma unroll
        for (int i = 0; i < 4; ++i) t8[i] = fmaxf(t8[i], t8[i + 4]);
        float tmax = fmaxf(fmaxf(t8[0], t8[1]), fmaxf(t8[2], t8[3]));
        tmax = fmaxf(tmax, __shfl_xor(tmax, 32, 64));   // cross-half

        // T13 defer-max: only rescale when max grew past threshold
        if (__any(tmax > m_run + DEFER_THR)) {
            float mnew = fmaxf(m_run, tmax);
            float scale = exp2f(m_run - mnew);
            m_run = mnew;
            l_run *= scale;
#pragma unroll
            for (int jn = 0; jn < 16; ++jn) {
                float sc = __shfl(scale, (jn & 3) + 8 * (jn >> 2) + 4 * hi, 64);
                accO[0][jn] *= sc;
                accO[1][jn] *= sc;
            }
        }
#pragma unroll
        for (int i = 0; i < 32; ++i) s[i] = exp2f(s[i] - m_run);
        // tree sum
        float u8[8];
#pragma unroll
        for (int i = 0; i < 8; ++i)
            u8[i] = (s[i] + s[i + 8]) + (s[i + 16] + s[i + 24]);
#pragma unroll
        for (int i = 0; i < 4; ++i) u8[i] += u8[i + 4];
        float psum = (u8[0] + u8[1]) + (u8[2] + u8[3]);
        psum += __shfl_xor(psum, 32, 64);               // cross-half
        l_run += psum;

        // P -> PV A-operand in registers (cvt_pk + permlane32_swap;
        // operands SSA-distinct -> no coalescing hazard)
        v8s PA[4];
#pragma unroll
        for (int t = 0; t < 2; ++t)
#pragma unroll
            for (int sf = 0; sf < 2; ++sf) {
                int base = t * 16 + sf * 8;
                unsigned x0 = cvtpk(s[base + 0], s[base + 1]);
                unsigned x1 = cvtpk(s[base + 2], s[base + 3]);
                unsigned y0 = cvtpk(s[base + 4], s[base + 5]);
                unsigned y1 = cvtpk(s[base + 6], s[base + 7]);
                asm volatile("v_permlane32_swap_b32 %0, %1" : "+v"(x0), "+v"(y0));
                asm volatile("v_permlane32_swap_b32 %0, %1" : "+v"(x1), "+v"(y1));
                v4u wv; wv[0] = x0; wv[1] = x1; wv[2] = y0; wv[3] = y1;
                union { v4u u; v8s s8; } cvt; cvt.u = wv;
                PA[t * 2 + sf] = cvt.s8;
            }

        // PV: A=P (in-reg), B=V[kp][d] via Vs=[d][kp]
        __builtin_amdgcn_s_setprio(1);
#pragma unroll
        for (int ks = 0; ks < 4; ++ks) {
            v8s v0f = *(const v8s*)((char*)Vb + swz(lq, ks * 32 + hi * 16));
            v8s v1f = *(const v8s*)((char*)Vb + swz(32 + lq, ks * 32 + hi * 16));
            accO[0] = MFMA32(PA[ks], v0f, accO[0]);
            accO[1] = MFMA32(PA[ks], v1f, accO[1]);
        }
        __builtin_amdgcn_s_setprio(0);
    };

    // ---- prologue: clean VMEM slate, then pen + tile0 prefetch ----
    asm volatile("s_waitcnt vmcnt(0)" ::: "memory");
    asm volatile("" : : "v"(qf[0]), "v"(qf[1]), "v"(qf[2]), "v"(qf[3]));
#pragma unroll
    for (int i = 0; i < 2; ++i)               // 4KB pen row, 2 calls/wave
        async16((char*)penS + (w * 2 + i) * 1024, pp + (w * 2 + i) * 512 + l * 8);
    stage(0, 0);

    // ---- main loop: 2 barriers + counted vmcnt(8) (kt+1 loads stay in flight)
    for (int kt = 0; kt < NT; ++kt) {
        const int k0 = kt * 64;
        __builtin_amdgcn_s_barrier();         // B1: all waves done reading buf (kt+1)&1
        __builtin_amdgcn_sched_barrier(0);
        if (kt + 1 < NT) {
            stage(kt + 1, (kt + 1) & 1);
            asm volatile("s_waitcnt vmcnt(8)" ::: "memory");  // drain kt's loads
        } else {
            asm volatile("s_waitcnt vmcnt(0)" ::: "memory");
        }
        __builtin_amdgcn_sched_barrier(0);
        __builtin_amdgcn_s_barrier();         // B2: tile kt fully staged (all waves)
        __builtin_amdgcn_sched_barrier(0);    // rule #18: no ds_read hoisting
        short p0 = penS[k0 + lq], p1 = penS[k0 + lq + 32];
        chalf(kt, kt & 1, k0 + 63 > qmin, p0, p1);
    }

    // Rescue pass: rows whose causal-valid keys are ALL masked must tie with
    // future keys at exactly -CMASK (fp32 reference semantics). vmcnt is 0
    // here (last iter waited 0); plain __syncthreads path, rare.
    int kt = NT;
    while (kt < 32) {
        if (tid == 0) rflag = 0;
        __syncthreads();
        if (__any(m_run < -1e11f) && l == 0) rflag = 1;
        __syncthreads();
        if (!rflag) break;
        short p0 = penS[kt * 64 + lq], p1 = penS[kt * 64 + lq + 32];
        stage(kt, 0);
        __syncthreads();
        chalf(kt, 0, true, p0, p1);
        __syncthreads();
        ++kt;
    }

    // epilogue: rows q=(jn&3)+8*(jn>>2)+4*hi, cols d = dt*32+lq
    float inv = 1.0f / l_run;
#pragma unroll
    for (int jn = 0; jn < 16; ++jn) {
        int rowq = (jn & 3) + 8 * (jn >> 2) + 4 * hi;
        float iv = __shfl(inv, rowq, 64);
        int s_row = __shfl(q_glob, rowq, 64);          // original row index
        if (cy + w * 32 + rowq < nqv) {                // store only live rows
            size_t base = (size_t)(b * S_LEN + s_row) * 1024 + hd * 64 + lq;
            O[base]      = f2bf(accO[0][jn] * iv);
            O[base + 32] = f2bf(accO[1][jn] * iv);
        }
    }
}

// ---------------- output projection + bias + q_mask ----------------
__global__ __launch_bounds__(256)
void out_gemm(const short* __restrict__ A, const short* __restrict__ BT,
              const float* __restrict__ bias, const int* __restrict__ qmask,
              float* __restrict__ out) {
    __shared__ short As[128 * 64];
    __shared__ short Bs[128 * 64];
    const int tid = threadIdx.x;
    const int l = tid & 63, w = tid >> 6;
    const int g = l >> 4, ql = l & 15;
    const int m0 = blockIdx.x * 128, n0 = blockIdx.y * 128;
    const int wr = w >> 1, wc = w & 1;

    v4f acc[4][4] = {};

    for (int kt = 0; kt < 16; ++kt) {
        const int kk = kt * 64;
        __syncthreads();
#pragma unroll
        for (int i = 0; i < 4; ++i) {
            int ci = i * 256 + tid;
            int row = ci >> 3, c = ci & 7;
            async16((char*)As + (size_t)(i * 256 + w * 64) * 16,
                    A + (size_t)(m0 + row) * 1024 + kk + c * 8);
            async16((char*)Bs + (size_t)(i * 256 + w * 64) * 16,
                    BT + (size_t)(n0 + row) * 1024 + kk + c * 8);
        }
        __syncthreads();
#pragma unroll
        for (int ks = 0; ks < 2; ++ks) {
            v8s af[4], bfr[4];
#pragma unroll
            for (int mt = 0; mt < 4; ++mt)
                af[mt] = *(const v8s*)(As + (wr * 64 + mt * 16 + ql) * 64 + ks * 32 + g * 8);
#pragma unroll
            for (int nt = 0; nt < 4; ++nt)
                bfr[nt] = *(const v8s*)(Bs + (wc * 64 + nt * 16 + ql) * 64 + ks * 32 + g * 8);
#pragma unroll
            for (int mt = 0; mt < 4; ++mt)
#pragma unroll
                for (int nt = 0; nt < 4; ++nt)
                    acc[mt][nt] = MFMA16(af[mt], bfr[nt], acc[mt][nt]);
        }
    }

#pragma unroll
    for (int nt = 0; nt < 4; ++nt) {
        int col = n0 + wc * 64 + nt * 16 + ql;
        float bval = bias[col];
#pragma unroll
        for (int mt = 0; mt < 4; ++mt) {
#pragma unroll
            for (int r = 0; r < 4; ++r) {
                int gm = m0 + wr * 64 + mt * 16 + g * 4 + r;
                float vv = acc[mt][nt][r] + bval;
                vv *= (float)qmask[gm];
                out[(size_t)gm * 1024 + col] = vv;
            }
        }
    }
}

extern "C" void kernel_launch(void* const* d_in, const int* in_sizes, int n_in,
                              void* d_out, int out_size, void* d_ws, size_t ws_size,
                              hipStream_t stream) {
    (void)in_sizes; (void)n_in; (void)out_size; (void)ws_size;
    const float* q  = (const float*)d_in[0];
    const float* k  = (const float*)d_in[1];
    const float* v  = (const float*)d_in[2];
    const int* qmask = (const int*)d_in[3];
    const int* vmask = (const int*)d_in[4];
    const float* Wq = (const float*)d_in[5];
    const float* bq = (const float*)d_in[6];
    const float* Wk = (const float*)d_in[7];
    const float* bk = (const float*)d_in[8];
    const float* Wv = (const float*)d_in[9];
    const float* bv = (const float*)d_in[10];
    const float* Wo = (const float*)d_in[11];
    const float* bo = (const float*)d_in[12];
    float* out = (float*)d_out;

    char* ws = (char*)d_ws;
    const size_t MB = 1024 * 1024;
    short* Xq  = (short*)(ws + 0 * MB);
    short* Xk  = (short*)(ws + 16 * MB);
    short* Xv  = (short*)(ws + 32 * MB);
    short* WTq = (short*)(ws + 48 * MB);
    short* WTk = (short*)(ws + 50 * MB);
    short* WTv = (short*)(ws + 52 * MB);
    short* WTo = (short*)(ws + 54 * MB);
    short* QW  = (short*)(ws + 56 * MB);
    short* KW  = (short*)(ws + 72 * MB);
    short* VTb = (short*)(ws + 88 * MB);
    short* Ob  = (short*)(ws + 104 * MB);
    short* penC = (short*)(ws + 120 * MB);
    int* idxB  = (int*)(ws + 121 * MB);
    int* nqB   = (int*)(ws + 122 * MB);

    convert_f32_bf16<<<4096, 256, 0, stream>>>(q, Xq);
    convert_f32_bf16<<<4096, 256, 0, stream>>>(k, Xk);
    convert_f32_bf16<<<4096, 256, 0, stream>>>(v, Xv);
    transpose_w<<<dim3(32, 32), 256, 0, stream>>>(Wq, WTq);
    transpose_w<<<dim3(32, 32), 256, 0, stream>>>(Wk, WTk);
    transpose_w<<<dim3(32, 32), 256, 0, stream>>>(Wv, WTv);
    transpose_w<<<dim3(32, 32), 256, 0, stream>>>(Wo, WTo);
    build_pen<<<32, 256, 0, stream>>>(vmask, penC);
    compact_qmask<<<NB, 256, 0, stream>>>(qmask, idxB, nqB);

    proj_gemm<<<dim3(64, 8, 3), 256, 0, stream>>>(Xq, Xk, Xv, WTq, WTk, WTv,
                                                  bq, bk, bv, QW, KW, VTb);
    attn_kernel<<<dim3(64, 32), 128, 0, stream>>>(QW, KW, VTb, penC, idxB, nqB, Ob);
    out_gemm<<<dim3(64, 8), 256, 0, stream>>>(Ob, WTo, bo, qmask, out);
}